// Round 3
// baseline (26499.109 us; speedup 1.0000x reference)
//
#include <hip/hip_runtime.h>
#include <math.h>

#define T_DIM 256
#define B_DIM 64
#define KDIM 2048   // I*D == H*D
#define TBROWS 16384
#define NBLK 256    // persistent scan grid

constexpr float EPSF = 1e-15f;
constexpr float MAXN = 1.0f - 1e-5f;

typedef short bf16x8 __attribute__((ext_vector_type(8)));
typedef float f32x4 __attribute__((ext_vector_type(4)));

__device__ __forceinline__ float atanh_ref(float x) {
  x = fminf(x, 1.0f - EPSF);
  return 0.5f * (log1pf(x + EPSF) - log1pf(EPSF - x));
}

__device__ __forceinline__ unsigned short f2bf(float x) {
  unsigned int u = __float_as_uint(x);
  unsigned int r = (u + 0x7fffu + ((u >> 16) & 1u)) >> 16;
  return (unsigned short)r;
}
__device__ __forceinline__ float bf2f(unsigned short h) {
  return __uint_as_float(((unsigned int)h) << 16);
}

__device__ __forceinline__ void gload16(const void* g, void* l) {
  __builtin_amdgcn_global_load_lds(
      (const __attribute__((address_space(1))) unsigned int*)g,
      (__attribute__((address_space(3))) unsigned int*)l, 16, 0, 0);
}

// reduce two values across a 256-thread block; result broadcast to all threads
__device__ __forceinline__ void block_reduce2(float& v0, float& v1, float* lds) {
  #pragma unroll
  for (int off = 32; off > 0; off >>= 1) {
    v0 += __shfl_down(v0, off, 64);
    v1 += __shfl_down(v1, off, 64);
  }
  const int lane = threadIdx.x & 63;
  const int wid  = threadIdx.x >> 6;
  if (lane == 0) { lds[wid * 2] = v0; lds[wid * 2 + 1] = v1; }
  __syncthreads();
  if (threadIdx.x == 0) {
    float s0 = 0.f, s1 = 0.f;
    #pragma unroll
    for (int w = 0; w < 4; ++w) { s0 += lds[w * 2]; s1 += lds[w * 2 + 1]; }
    lds[0] = s0; lds[1] = s1;
  }
  __syncthreads();
  v0 = lds[0]; v1 = lds[1];
  __syncthreads();
}

// grid barrier: sense-reversing, agent-scope atomics. All NBLK blocks must be
// co-resident (1024 waves << 8192-wave capacity -> guaranteed).
__device__ __forceinline__ void gbar(unsigned* cnt, unsigned* gen) {
  __threadfence();
  __syncthreads();
  if (threadIdx.x == 0) {
    unsigned g = __hip_atomic_load(gen, __ATOMIC_RELAXED, __HIP_MEMORY_SCOPE_AGENT);
    unsigned v = __hip_atomic_fetch_add(cnt, 1u, __ATOMIC_ACQ_REL, __HIP_MEMORY_SCOPE_AGENT);
    if (v == NBLK - 1u) {
      __hip_atomic_store(cnt, 0u, __ATOMIC_RELAXED, __HIP_MEMORY_SCOPE_AGENT);
      __hip_atomic_fetch_add(gen, 1u, __ATOMIC_RELEASE, __HIP_MEMORY_SCOPE_AGENT);
    } else {
      while (__hip_atomic_load(gen, __ATOMIC_ACQUIRE, __HIP_MEMORY_SCOPE_AGENT) == g)
        __builtin_amdgcn_s_sleep(1);
    }
  }
  __syncthreads();
}

// ---------------------------------------------------------------------------
// Convert inputs to bf16 hi/lo planes, permuting rows (b*256+t) -> (t*64+b).
// ---------------------------------------------------------------------------
__global__ __launch_bounds__(256) void convert_a(const float* __restrict__ inp,
                                                 unsigned short* __restrict__ Ah,
                                                 unsigned short* __restrict__ Al) {
  const int i = blockIdx.x;
  const int r = ((i & 255) << 6) + (i >> 8);
  const float* src = inp + (size_t)i * KDIM;
  unsigned short* dh = Ah + (size_t)r * KDIM;
  unsigned short* dl = Al + (size_t)r * KDIM;
  const int base = threadIdx.x * 8;
  float4 v0 = *(const float4*)(src + base);
  float4 v1 = *(const float4*)(src + base + 4);
  float f[8] = {v0.x, v0.y, v0.z, v0.w, v1.x, v1.y, v1.z, v1.w};
  unsigned short h[8], l[8];
  #pragma unroll
  for (int j = 0; j < 8; ++j) {
    unsigned short hb = f2bf(f[j]);
    h[j] = hb;
    l[j] = f2bf(f[j] - bf2f(hb));
  }
  *(bf16x8*)(dh + base) = *(bf16x8*)h;
  *(bf16x8*)(dl + base) = *(bf16x8*)l;
}

// ---------------------------------------------------------------------------
// Transpose + convert M (2048x2048) into M^T bf16 hi/lo: Bt[n][k] = M[k][n].
// ---------------------------------------------------------------------------
__global__ __launch_bounds__(256) void convert_bt(const float* __restrict__ M,
                                                  unsigned short* __restrict__ Bh,
                                                  unsigned short* __restrict__ Bl) {
  __shared__ float t[64][65];
  const int k0 = blockIdx.y * 64, nn0 = blockIdx.x * 64;
  const int tid = threadIdx.x;
  #pragma unroll
  for (int j = 0; j < 4; ++j) {
    int idx = tid + j * 256;
    int r = idx >> 4, c4 = (idx & 15) * 4;
    float4 v = *(const float4*)(M + (size_t)(k0 + r) * KDIM + nn0 + c4);
    t[r][c4 + 0] = v.x; t[r][c4 + 1] = v.y; t[r][c4 + 2] = v.z; t[r][c4 + 3] = v.w;
  }
  __syncthreads();
  #pragma unroll
  for (int j = 0; j < 4; ++j) {
    int idx = tid + j * 256;
    int n = idx >> 4, ks = (idx & 15) * 4;
    unsigned short hh[4], ll[4];
    #pragma unroll
    for (int q = 0; q < 4; ++q) {
      float x = t[ks + q][n];
      unsigned short hb = f2bf(x);
      hh[q] = hb;
      ll[q] = f2bf(x - bf2f(hb));
    }
    *(ushort4*)(Bh + (size_t)(nn0 + n) * KDIM + k0 + ks) = *(ushort4*)hh;
    *(ushort4*)(Bl + (size_t)(nn0 + n) * KDIM + k0 + ks) = *(ushort4*)ll;
  }
}

// ---------------------------------------------------------------------------
// bf16x3-split MFMA GEMM for Ux (unchanged from round 1; passes).
// ---------------------------------------------------------------------------
__global__ __launch_bounds__(256) void gemm_mfma3(const unsigned short* __restrict__ Ah,
                                                  const unsigned short* __restrict__ Al,
                                                  const unsigned short* __restrict__ Bh,
                                                  const unsigned short* __restrict__ Bl,
                                                  float* __restrict__ C) {
  __shared__ unsigned char LAh[8192], LAl[8192], LBh[8192], LBl[8192];
  const int tid = threadIdx.x;
  const int lane = tid & 63;
  const int w = tid >> 6;
  const int wr = w >> 1, wc = w & 1;
  const int m0 = blockIdx.x * 128;
  const int n0 = blockIdx.y * 128;

  f32x4 acc[4][4] = {};

  for (int k0 = 0; k0 < KDIM; k0 += 32) {
    #pragma unroll
    for (int j = 0; j < 2; ++j) {
      int c = j * 256 + tid;
      int row = c >> 2;
      int sp = (c & 3) ^ (row & 3);
      size_t aoff = (size_t)(m0 + row) * KDIM + k0 + sp * 8;
      size_t boff = (size_t)(n0 + row) * KDIM + k0 + sp * 8;
      int ldsb = (j * 256 + w * 64) * 16;
      gload16(Ah + aoff, LAh + ldsb);
      gload16(Al + aoff, LAl + ldsb);
      gload16(Bh + boff, LBh + ldsb);
      gload16(Bl + boff, LBl + ldsb);
    }
    __syncthreads();
    bf16x8 ah[4], al[4], bh[4], bl[4];
    #pragma unroll
    for (int i = 0; i < 4; ++i) {
      int arow = wr * 64 + i * 16 + (lane & 15);
      int abyte = arow * 64 + (((lane >> 4) ^ (arow & 3)) * 16);
      ah[i] = *(const bf16x8*)(LAh + abyte);
      al[i] = *(const bf16x8*)(LAl + abyte);
      int brow = wc * 64 + i * 16 + (lane & 15);
      int bbyte = brow * 64 + (((lane >> 4) ^ (brow & 3)) * 16);
      bh[i] = *(const bf16x8*)(LBh + bbyte);
      bl[i] = *(const bf16x8*)(LBl + bbyte);
    }
    #pragma unroll
    for (int i = 0; i < 4; ++i)
      #pragma unroll
      for (int jn = 0; jn < 4; ++jn) {
        acc[i][jn] = __builtin_amdgcn_mfma_f32_16x16x32_bf16(ah[i], bh[jn], acc[i][jn], 0, 0, 0);
        acc[i][jn] = __builtin_amdgcn_mfma_f32_16x16x32_bf16(ah[i], bl[jn], acc[i][jn], 0, 0, 0);
        acc[i][jn] = __builtin_amdgcn_mfma_f32_16x16x32_bf16(al[i], bh[jn], acc[i][jn], 0, 0, 0);
      }
    __syncthreads();
  }
  #pragma unroll
  for (int i = 0; i < 4; ++i) {
    int grow = m0 + wr * 64 + i * 16 + ((lane >> 4) << 2);
    #pragma unroll
    for (int jn = 0; jn < 4; ++jn) {
      int gcol = n0 + wc * 64 + jn * 16 + (lane & 15);
      #pragma unroll
      for (int r = 0; r < 4; ++r)
        C[(size_t)(grow + r) * KDIM + gcol] = acc[i][jn][r];
    }
  }
}

// ---------------------------------------------------------------------------
// Mobius epilogue for the big GEMM (in-place on Mx -> Ux). One block per row.
// ---------------------------------------------------------------------------
__global__ __launch_bounds__(256) void ux_epilogue(const float* __restrict__ inp,
                                                   float* __restrict__ Mx) {
  const int r = blockIdx.x;
  const int t = r >> 6, b = r & 63;
  const float* xrow = inp + ((size_t)(b * T_DIM + t)) * KDIM;
  float* mrow = Mx + (size_t)r * KDIM;
  const int tid = threadIdx.x;
  __shared__ float lds[8];
  float xs2 = 0.f, ms2 = 0.f;
  float m[8];
  #pragma unroll
  for (int j = 0; j < 8; ++j) {
    const int col = tid + j * 256;
    float xv = xrow[col] + EPSF;
    xs2 += xv * xv;
    float mv = mrow[col];
    m[j] = mv;
    ms2 += mv * mv;
  }
  block_reduce2(xs2, ms2, lds);
  float xn = sqrtf(xs2);
  float mnr = sqrtf(ms2);
  float mxn = mnr + EPSF;
  float s = tanhf((mxn / xn) * atanh_ref(xn)) / mxn;
  float na = s * mnr;
  float pf = fminf(1.0f, MAXN / fmaxf(na, EPSF));
  float sc = s * pf;
  #pragma unroll
  for (int j = 0; j < 8; ++j)
    mrow[tid + j * 256] = m[j] * sc;
}

// ---------------------------------------------------------------------------
// Init for the persistent scan: h = 0+EPS (bf16 hi/lo), hn2 partials (parity 0),
// bvbv scalar, barrier counters.
// ---------------------------------------------------------------------------
__global__ __launch_bounds__(256) void scan_init(unsigned short* __restrict__ hh_,
                                                 unsigned short* __restrict__ hl_,
                                                 float* __restrict__ pd,
                                                 const float* __restrict__ bvec,
                                                 float* __restrict__ bvbvp,
                                                 unsigned* __restrict__ sync) {
  const int bx = blockIdx.x;  // 64 blocks
  const int tid = threadIdx.x;
  const unsigned short he = f2bf(EPSF);
  const unsigned short le = f2bf(EPSF - bf2f(he));
  #pragma unroll
  for (int j = 0; j < 8; ++j) {
    int c = tid + j * 256;
    hh_[(size_t)bx * KDIM + c] = he;
    hl_[(size_t)bx * KDIM + c] = le;
  }
  if (bx == 0) {
    for (int i = tid; i < 8192; i += 256) {
      int rg = i >> 12, rem = i & 4095, cs = rem >> 5, rr = rem & 31;
      pd[(((size_t)rg * 128 + cs) * 32 + rr) * 8 + 5] = 16.0f * EPSF * EPSF;
    }
    if (tid < 2) sync[tid] = 0u;
  }
  if (bx == 1) {
    __shared__ float lds[8];
    float s = 0.f;
    #pragma unroll
    for (int j = 0; j < 8; ++j) {
      float v = bvec[tid + j * 256] + EPSF;
      s += v * v;
    }
    float dummy = 0.f;
    block_reduce2(s, dummy, lds);
    if (tid == 0) *bvbvp = s;
  }
}

// ---------------------------------------------------------------------------
// Persistent whole-scan kernel. 256 blocks x 256 threads.
// Block: rowgroup rg (32 batch rows) x colslice cs (16 cols), XCD-swizzled so
// each XCD's W^T panel (2048x256 bf16 hi+lo = 2MB) stays L2-resident.
// Per step: bf16x3 MFMA Mh tile -> 5 dot partials -> gbar -> reduce + scalar
// chain (1 reduction total, algebraically collapsed) -> h/out write -> gbar.
// ---------------------------------------------------------------------------
__global__ __launch_bounds__(256) void scan_coop(const unsigned short* __restrict__ Wth,
                                                 const unsigned short* __restrict__ Wtl,
                                                 unsigned short* __restrict__ hh_,
                                                 unsigned short* __restrict__ hl_,
                                                 const float* __restrict__ Ux,
                                                 const float* __restrict__ bvec,
                                                 float* __restrict__ pd,
                                                 const float* __restrict__ bvbvp,
                                                 unsigned* __restrict__ sync,
                                                 float* __restrict__ out) {
  const int tid = threadIdx.x;
  const int bx = blockIdx.x;
  const int lane = tid & 63;
  const int w = tid >> 6;
  const int rg = bx >> 7;                       // 0..1 (32 rows each)
  const int cs = (bx & 7) * 16 + ((bx >> 3) & 15);  // 0..127, XCD-grouped
  const int gc0 = cs * 16;
  const int r = tid >> 3;                       // row within 32
  const int b = rg * 32 + r;                    // batch row
  const int gc = gc0 + (tid & 7) * 2;           // global col (pair)

  __shared__ float wtmp[4][32][16];
  __shared__ float MhL[32][16];
  __shared__ float red[32][6];
  __shared__ float cf[32][3];

  const float bvbv = *bvbvp;
  const float bv0 = bvec[gc] + EPSF;
  const float bv1 = bvec[gc + 1] + EPSF;

  const int arow0 = (rg * 32 + (lane & 15)) * KDIM;
  const int arow1 = (rg * 32 + 16 + (lane & 15)) * KDIM;
  const int brow = (gc0 + (lane & 15)) * KDIM;
  const int ksub = w * 512 + (lane >> 4) * 8;

  unsigned* cnt = sync;
  unsigned* gen = sync + 1;

  for (int t = 0; t < T_DIM; ++t) {
    // ---- phase A: Mh tile (32x16) via bf16x3 MFMA, wave-split-K ----
    f32x4 acc0 = {}, acc1 = {};
    #pragma unroll 4
    for (int ks = 0; ks < 16; ++ks) {
      const int k0 = ksub + ks * 32;
      bf16x8 a0h = *(const bf16x8*)(hh_ + arow0 + k0);
      bf16x8 a0l = *(const bf16x8*)(hl_ + arow0 + k0);
      bf16x8 a1h = *(const bf16x8*)(hh_ + arow1 + k0);
      bf16x8 a1l = *(const bf16x8*)(hl_ + arow1 + k0);
      bf16x8 bh = *(const bf16x8*)(Wth + brow + k0);
      bf16x8 bl = *(const bf16x8*)(Wtl + brow + k0);
      acc0 = __builtin_amdgcn_mfma_f32_16x16x32_bf16(a0h, bh, acc0, 0, 0, 0);
      acc0 = __builtin_amdgcn_mfma_f32_16x16x32_bf16(a0h, bl, acc0, 0, 0, 0);
      acc0 = __builtin_amdgcn_mfma_f32_16x16x32_bf16(a0l, bh, acc0, 0, 0, 0);
      acc1 = __builtin_amdgcn_mfma_f32_16x16x32_bf16(a1h, bh, acc1, 0, 0, 0);
      acc1 = __builtin_amdgcn_mfma_f32_16x16x32_bf16(a1h, bl, acc1, 0, 0, 0);
      acc1 = __builtin_amdgcn_mfma_f32_16x16x32_bf16(a1l, bh, acc1, 0, 0, 0);
    }
    #pragma unroll
    for (int q = 0; q < 4; ++q) {
      wtmp[w][(lane >> 4) * 4 + q][lane & 15] = acc0[q];
      wtmp[w][16 + (lane >> 4) * 4 + q][lane & 15] = acc1[q];
    }
    __syncthreads();
    #pragma unroll
    for (int e = tid; e < 512; e += 256) {
      int rr = e >> 4, cc = e & 15;
      MhL[rr][cc] = wtmp[0][rr][cc] + wtmp[1][rr][cc] + wtmp[2][rr][cc] + wtmp[3][rr][cc];
    }
    __syncthreads();
    const float mh0 = MhL[r][(tid & 7) * 2];
    const float mh1 = MhL[r][(tid & 7) * 2 + 1];
    const float ux0 = Ux[((size_t)t * 64 + b) * KDIM + gc] + EPSF;
    const float ux1 = Ux[((size_t)t * 64 + b) * KDIM + gc + 1] + EPSF;
    float dt0 = mh0 * mh0 + mh1 * mh1;
    float dt1 = mh0 * ux0 + mh1 * ux1;
    float dt2 = ux0 * ux0 + ux1 * ux1;
    float dt3 = mh0 * bv0 + mh1 * bv1;
    float dt4 = ux0 * bv0 + ux1 * bv1;
    #pragma unroll
    for (int off = 4; off > 0; off >>= 1) {
      dt0 += __shfl_down(dt0, off, 8);
      dt1 += __shfl_down(dt1, off, 8);
      dt2 += __shfl_down(dt2, off, 8);
      dt3 += __shfl_down(dt3, off, 8);
      dt4 += __shfl_down(dt4, off, 8);
    }
    const int par = t & 1;
    if ((tid & 7) == 0) {
      float* slot = pd + ((((size_t)par * 2 + rg) * 128 + cs) * 32 + r) * 8;
      slot[0] = dt0; slot[1] = dt1; slot[2] = dt2; slot[3] = dt3; slot[4] = dt4;
    }
    gbar(cnt, gen);

    // ---- phase B: reduce partials, scalar chain, elementwise update ----
    if (tid < 192) {
      int rr = tid / 6, v = tid - rr * 6;
      const float* base = pd + (((size_t)par * 2 + rg) * 128) * 256 + rr * 8 + v;
      float s = 0.f;
      for (int q = 0; q < 128; ++q) s += base[q * 256];
      red[rr][v] = s;
    }
    __syncthreads();
    if (tid < 32) {
      const float mn2 = red[tid][0], Mhux = red[tid][1], uxux = red[tid][2];
      const float Mhbv = red[tid][3], uxbv = red[tid][4], hn2 = red[tid][5];
      const float hn = sqrtf(hn2);
      const float mnr = sqrtf(mn2);
      const float mxn = mnr + EPSF;
      const float s = tanhf((mxn / hn) * atanh_ref(hn)) / mxn;
      const float n_a = s * mnr;
      const float pfa = fminf(1.0f, MAXN / fmaxf(n_a, EPSF));
      const float sa = s * pfa;
      const float duv = 2.0f * sa * Mhux;
      const float nv = uxux;
      const float na = sa * sa * mn2;
      const float denom = 1.0f + duv + na * nv;
      const float c1 = (1.0f + duv + nv) / denom;
      const float c2 = (1.0f - na) / denom;
      const float r1n2 = c1 * c1 * na + 2.0f * c1 * c2 * sa * Mhux + c2 * c2 * uxux;
      const float pf1 = fminf(1.0f, MAXN / fmaxf(sqrtf(r1n2), EPSF));
      const float Sr1bv = c1 * sa * Mhbv + c2 * uxbv;
      const float duv2 = 2.0f * pf1 * Sr1bv;
      const float na2 = pf1 * pf1 * r1n2;
      const float denom2 = 1.0f + duv2 + na2 * bvbv;
      const float d1 = (1.0f + duv2 + bvbv) / denom2;
      const float d2 = (1.0f - na2) / denom2;
      const float r2n2 = d1 * d1 * na2 + 2.0f * d1 * d2 * pf1 * Sr1bv + d2 * d2 * bvbv;
      const float pf2 = fminf(1.0f, MAXN / fmaxf(sqrtf(r2n2), EPSF));
      cf[tid][0] = pf2 * d1 * pf1 * c1 * sa;  // K_mh
      cf[tid][1] = pf2 * d1 * pf1 * c2;       // K_ux
      cf[tid][2] = pf2 * d2;                  // K_bv
    }
    __syncthreads();
    const float Km = cf[r][0], Ku = cf[r][1], Kb = cf[r][2];
    const float h0 = Km * mh0 + Ku * ux0 + Kb * bv0;
    const float h1 = Km * mh1 + Ku * ux1 + Kb * bv1;
    *(float2*)(out + ((size_t)b * T_DIM + t) * KDIM + gc) = make_float2(h0, h1);
    const float hp0 = h0 + EPSF, hp1 = h1 + EPSF;
    const unsigned short e0 = f2bf(hp0), e1 = f2bf(hp1);
    ushort2 hhv; hhv.x = e0; hhv.y = e1;
    ushort2 hlv; hlv.x = f2bf(hp0 - bf2f(e0)); hlv.y = f2bf(hp1 - bf2f(e1));
    *(ushort2*)(hh_ + (size_t)b * KDIM + gc) = hhv;
    *(ushort2*)(hl_ + (size_t)b * KDIM + gc) = hlv;
    float hn2p = hp0 * hp0 + hp1 * hp1;
    #pragma unroll
    for (int off = 4; off > 0; off >>= 1) hn2p += __shfl_down(hn2p, off, 8);
    if ((tid & 7) == 0)
      pd[((((size_t)(par ^ 1) * 2 + rg) * 128 + cs) * 32 + r) * 8 + 5] = hn2p;
    gbar(cnt, gen);
  }
}

// ---------------------------------------------------------------------------
// Fallback kernels (small-workspace paths) — unchanged from round 1.
// ---------------------------------------------------------------------------
__global__ __launch_bounds__(256) void gemm64_splitk(const float* __restrict__ A,
                                                     size_t arstride,
                                                     const float* __restrict__ Bm,
                                                     float* __restrict__ part) {
  const int n0 = blockIdx.x * 64;
  const int kz = blockIdx.y;
  const int kbeg = kz * 256;
  __shared__ float As[16][68];
  __shared__ float Bs[16][64];
  const int tid = threadIdx.x;
  const int tx = tid & 15, ty = tid >> 4;
  const int ai = tid >> 2, ak = (tid & 3) * 4;
  const int bk = tid >> 4, bn = (tid & 15) * 4;
  const float* Arow = A + (size_t)ai * arstride;
  float acc[4][4] = {};
  for (int kt = 0; kt < 16; ++kt) {
    const int k0 = kbeg + kt * 16;
    float4 av = *(const float4*)(Arow + k0 + ak);
    As[ak + 0][ai] = av.x + EPSF;
    As[ak + 1][ai] = av.y + EPSF;
    As[ak + 2][ai] = av.z + EPSF;
    As[ak + 3][ai] = av.w + EPSF;
    float4 bv = *(const float4*)(Bm + (size_t)(k0 + bk) * KDIM + n0 + bn);
    *(float4*)&Bs[bk][bn] = bv;
    __syncthreads();
    #pragma unroll
    for (int k = 0; k < 16; ++k) {
      float4 a4 = *(const float4*)&As[k][ty * 4];
      float4 b4 = *(const float4*)&Bs[k][tx * 4];
      float a[4] = {a4.x, a4.y, a4.z, a4.w};
      float bb[4] = {b4.x, b4.y, b4.z, b4.w};
      #pragma unroll
      for (int i = 0; i < 4; ++i)
        #pragma unroll
        for (int j = 0; j < 4; ++j)
          acc[i][j] = fmaf(a[i], bb[j], acc[i][j]);
    }
    __syncthreads();
  }
  #pragma unroll
  for (int i = 0; i < 4; ++i) {
    float4 o = make_float4(acc[i][0], acc[i][1], acc[i][2], acc[i][3]);
    *(float4*)(part + ((size_t)kz * 64 + ty * 4 + i) * KDIM + n0 + tx * 4) = o;
  }
}

__global__ __launch_bounds__(256) void mob_from_parts(const float* __restrict__ part,
                                                      const float* __restrict__ xbase,
                                                      size_t xstride,
                                                      float* __restrict__ outrows) {
  const int b = blockIdx.x;
  const int tid = threadIdx.x;
  __shared__ float lds[8];
  const float* xrow = xbase + (size_t)b * xstride;
  float xs2 = 0.f, ms2 = 0.f;
  float m[8];
  #pragma unroll
  for (int j = 0; j < 8; ++j) {
    const int col = tid + j * 256;
    float xv = xrow[col] + EPSF;
    xs2 += xv * xv;
    float mv = 0.f;
    for (int kz = 0; kz < 8; ++kz)
      mv += part[((size_t)kz * 64 + b) * KDIM + col];
    m[j] = mv;
    ms2 += mv * mv;
  }
  block_reduce2(xs2, ms2, lds);
  float xn = sqrtf(xs2);
  float mnr = sqrtf(ms2);
  float mxn = mnr + EPSF;
  float s = tanhf((mxn / xn) * atanh_ref(xn)) / mxn;
  float na = s * mnr;
  float pf = fminf(1.0f, MAXN / fmaxf(na, EPSF));
  float sc = s * pf;
  #pragma unroll
  for (int j = 0; j < 8; ++j)
    outrows[(size_t)b * KDIM + tid + j * 256] = m[j] * sc;
}

__global__ __launch_bounds__(256) void step_mobius(const float* __restrict__ part,
                                                   float* __restrict__ h,
                                                   const float* __restrict__ uxrows,
                                                   const float* __restrict__ bvec,
                                                   float* __restrict__ out,
                                                   int t) {
  const int b = blockIdx.x;
  const int tid = threadIdx.x;
  __shared__ float lds[8];
  float mh[8], uxv[8], bv[8];
  float hn2 = 0.f, mn2 = 0.f;
  #pragma unroll
  for (int j = 0; j < 8; ++j) {
    const int col = tid + j * 256;
    float x = h[(size_t)b * KDIM + col] + EPSF;
    hn2 += x * x;
    float m = 0.f;
    for (int kz = 0; kz < 8; ++kz)
      m += part[((size_t)kz * 64 + b) * KDIM + col];
    mh[j] = m;
    mn2 += m * m;
    uxv[j] = uxrows[(size_t)b * KDIM + col] + EPSF;
    bv[j] = bvec[col] + EPSF;
  }
  block_reduce2(hn2, mn2, lds);
  float hn = sqrtf(hn2);
  float mnr = sqrtf(mn2);
  float mxn = mnr + EPSF;
  float s = tanhf((mxn / hn) * atanh_ref(hn)) / mxn;
  float n_a = s * mnr;
  float pfa = fminf(1.0f, MAXN / fmaxf(n_a, EPSF));
  float sa = s * pfa;
  float a[8];
  float duv = 0.f, nv = 0.f;
  #pragma unroll
  for (int j = 0; j < 8; ++j) {
    a[j] = sa * mh[j];
    duv += a[j] * uxv[j];
    nv += uxv[j] * uxv[j];
  }
  block_reduce2(duv, nv, lds);
  duv *= 2.0f;
  float na = sa * sa * mn2;
  float denom = 1.0f + duv + na * nv;
  float c1 = (1.0f + duv + nv) / denom;
  float c2 = (1.0f - na) / denom;
  float r1[8];
  float r1n2 = 0.f, dummy = 0.f;
  #pragma unroll
  for (int j = 0; j < 8; ++j) {
    r1[j] = c1 * a[j] + c2 * uxv[j];
    r1n2 += r1[j] * r1[j];
  }
  block_reduce2(r1n2, dummy, lds);
  float n1 = sqrtf(r1n2);
  float pf1 = fminf(1.0f, MAXN / fmaxf(n1, EPSF));
  float duv2 = 0.f, nv2 = 0.f;
  #pragma unroll
  for (int j = 0; j < 8; ++j) {
    r1[j] *= pf1;
    duv2 += r1[j] * bv[j];
    nv2 += bv[j] * bv[j];
  }
  block_reduce2(duv2, nv2, lds);
  duv2 *= 2.0f;
  float na2 = pf1 * pf1 * r1n2;
  float denom2 = 1.0f + duv2 + na2 * nv2;
  float d1 = (1.0f + duv2 + nv2) / denom2;
  float d2 = (1.0f - na2) / denom2;
  float r2[8];
  float r2n2 = 0.f;
  dummy = 0.f;
  #pragma unroll
  for (int j = 0; j < 8; ++j) {
    r2[j] = d1 * r1[j] + d2 * bv[j];
    r2n2 += r2[j] * r2[j];
  }
  block_reduce2(r2n2, dummy, lds);
  float n2 = sqrtf(r2n2);
  float pf2 = fminf(1.0f, MAXN / fmaxf(n2, EPSF));
  #pragma unroll
  for (int j = 0; j < 8; ++j) {
    const int col = tid + j * 256;
    float vout = r2[j] * pf2;
    h[(size_t)b * KDIM + col] = vout;
    out[((size_t)b * T_DIM + t) * KDIM + col] = vout;
  }
}

extern "C" void kernel_launch(void* const* d_in, const int* in_sizes, int n_in,
                              void* d_out, int out_size, void* d_ws, size_t ws_size,
                              hipStream_t stream) {
  const float* inp  = (const float*)d_in[0];
  const float* wm   = (const float*)d_in[1];
  const float* um   = (const float*)d_in[2];
  const float* bvec = (const float*)d_in[3];
  float* out = (float*)d_out;
  char* ws = (char*)d_ws;

  const size_t UXB  = (size_t)TBROWS * KDIM * 4;   // 134.2 MB
  const size_t AHL  = (size_t)TBROWS * KDIM * 2;   // 67.1 MB
  const size_t BTB  = (size_t)KDIM * KDIM * 2;     // 8.4 MB
  const size_t HB16 = (size_t)B_DIM * KDIM * 2;    // 256 KB
  const size_t PDB  = (size_t)2 * 2 * 128 * 32 * 8 * 4;  // 2 MB
  const size_t META = 256;
  const size_t HFP  = (size_t)B_DIM * KDIM * 4;    // 512 KB
  const size_t PART = (size_t)8 * B_DIM * KDIM * 4; // 4 MB

  size_t off = 0;
  float* Ux = (float*)(ws + off); off += UXB;
  unsigned short* Ah = (unsigned short*)(ws + off); off += AHL;
  unsigned short* Al = (unsigned short*)(ws + off); off += AHL;
  unsigned short* Bh = (unsigned short*)(ws + off); off += BTB;
  unsigned short* Bl = (unsigned short*)(ws + off); off += BTB;
  unsigned short* Wth = (unsigned short*)(ws + off); off += BTB;
  unsigned short* Wtl = (unsigned short*)(ws + off); off += BTB;
  unsigned short* hh = (unsigned short*)(ws + off); off += HB16;
  unsigned short* hl = (unsigned short*)(ws + off); off += HB16;
  float* pd = (float*)(ws + off); off += PDB;
  float* bvbvp = (float*)(ws + off);
  unsigned* syncp = (unsigned*)(ws + off + 64); off += META;
  float* hfp = (float*)(ws + off); off += HFP;
  float* part = (float*)(ws + off); off += PART;
  const size_t NEED_COOP = off;
  const size_t NEED_MFMA = UXB + 2 * AHL + 2 * BTB + HFP + PART;
  const size_t NEED_FP32 = UXB + HFP + PART;

  if (ws_size >= NEED_COOP) {
    convert_a<<<TBROWS, 256, 0, stream>>>(inp, Ah, Al);
    convert_bt<<<dim3(32, 32), 256, 0, stream>>>(um, Bh, Bl);
    convert_bt<<<dim3(32, 32), 256, 0, stream>>>(wm, Wth, Wtl);
    scan_init<<<B_DIM, 256, 0, stream>>>(hh, hl, pd, bvec, bvbvp, syncp);
    gemm_mfma3<<<dim3(128, 16), 256, 0, stream>>>(Ah, Al, Bh, Bl, Ux);
    ux_epilogue<<<TBROWS, 256, 0, stream>>>(inp, Ux);
    scan_coop<<<NBLK, 256, 0, stream>>>(Wth, Wtl, hh, hl, Ux, bvec, pd, bvbvp,
                                        syncp, out);
  } else if (ws_size >= NEED_MFMA) {
    float* Ux2 = (float*)ws;
    unsigned short* Ah2 = (unsigned short*)(ws + UXB);
    unsigned short* Al2 = (unsigned short*)(ws + UXB + AHL);
    unsigned short* Bh2 = (unsigned short*)(ws + UXB + 2 * AHL);
    unsigned short* Bl2 = (unsigned short*)(ws + UXB + 2 * AHL + BTB);
    float* h2 = (float*)(ws + UXB + 2 * AHL + 2 * BTB);
    float* part2 = (float*)(ws + UXB + 2 * AHL + 2 * BTB + HFP);
    hipMemsetAsync(h2, 0, HFP, stream);
    convert_a<<<TBROWS, 256, 0, stream>>>(inp, Ah2, Al2);
    convert_bt<<<dim3(32, 32), 256, 0, stream>>>(um, Bh2, Bl2);
    gemm_mfma3<<<dim3(128, 16), 256, 0, stream>>>(Ah2, Al2, Bh2, Bl2, Ux2);
    ux_epilogue<<<TBROWS, 256, 0, stream>>>(inp, Ux2);
    for (int t = 0; t < T_DIM; ++t) {
      gemm64_splitk<<<dim3(32, 8), 256, 0, stream>>>(h2, (size_t)KDIM, wm, part2);
      step_mobius<<<B_DIM, 256, 0, stream>>>(part2, h2, Ux2 + (size_t)t * B_DIM * KDIM,
                                             bvec, out, t);
    }
  } else {
    float* h2 = (float*)ws;
    float* part2 = (float*)(ws + HFP);
    float* partU = (float*)(ws + HFP + PART);
    float* uxstep = (float*)(ws + HFP + 2 * PART);
    hipMemsetAsync(h2, 0, HFP, stream);
    for (int t = 0; t < T_DIM; ++t) {
      const float* xt = inp + (size_t)t * KDIM;
      gemm64_splitk<<<dim3(32, 8), 256, 0, stream>>>(xt, (size_t)T_DIM * KDIM, um, partU);
      mob_from_parts<<<B_DIM, 256, 0, stream>>>(partU, xt, (size_t)T_DIM * KDIM, uxstep);
      gemm64_splitk<<<dim3(32, 8), 256, 0, stream>>>(h2, (size_t)KDIM, wm, part2);
      step_mobius<<<B_DIM, 256, 0, stream>>>(part2, h2, uxstep, bvec, out, t);
    }
  }
}

// Round 4
// 13355.099 us; speedup vs baseline: 1.9842x; 1.9842x over previous
//
#include <hip/hip_runtime.h>
#include <math.h>

#define T_DIM 256
#define B_DIM 64
#define KDIM 2048   // I*D == H*D
#define TBROWS 16384
#define NBLK 256    // persistent scan grid

constexpr float EPSF = 1e-15f;
constexpr float MAXN = 1.0f - 1e-5f;

typedef short bf16x8 __attribute__((ext_vector_type(8)));
typedef float f32x4 __attribute__((ext_vector_type(4)));

__device__ __forceinline__ float atanh_ref(float x) {
  x = fminf(x, 1.0f - EPSF);
  return 0.5f * (log1pf(x + EPSF) - log1pf(EPSF - x));
}

__device__ __forceinline__ unsigned short f2bf(float x) {
  unsigned int u = __float_as_uint(x);
  unsigned int r = (u + 0x7fffu + ((u >> 16) & 1u)) >> 16;
  return (unsigned short)r;
}
__device__ __forceinline__ float bf2f(unsigned short h) {
  return __uint_as_float(((unsigned int)h) << 16);
}

__device__ __forceinline__ void gload16(const void* g, void* l) {
  __builtin_amdgcn_global_load_lds(
      (const __attribute__((address_space(1))) unsigned int*)g,
      (__attribute__((address_space(3))) unsigned int*)l, 16, 0, 0);
}

// reduce two values across a 256-thread block; result broadcast to all threads
__device__ __forceinline__ void block_reduce2(float& v0, float& v1, float* lds) {
  #pragma unroll
  for (int off = 32; off > 0; off >>= 1) {
    v0 += __shfl_down(v0, off, 64);
    v1 += __shfl_down(v1, off, 64);
  }
  const int lane = threadIdx.x & 63;
  const int wid  = threadIdx.x >> 6;
  if (lane == 0) { lds[wid * 2] = v0; lds[wid * 2 + 1] = v1; }
  __syncthreads();
  if (threadIdx.x == 0) {
    float s0 = 0.f, s1 = 0.f;
    #pragma unroll
    for (int w = 0; w < 4; ++w) { s0 += lds[w * 2]; s1 += lds[w * 2 + 1]; }
    lds[0] = s0; lds[1] = s1;
  }
  __syncthreads();
  v0 = lds[0]; v1 = lds[1];
  __syncthreads();
}

// ---------------------------------------------------------------------------
// Flag-vector grid barrier. Each block release-stores target into its own
// flag slot; wave 0 polls all NBLK flags with RELAXED loads (no per-iteration
// L2 invalidate), one ACQUIRE fence per block after exit. Monotonic targets
// (>= check) make fast-block overtake safe. All NBLK blocks co-resident
// (1024 waves << 8192-wave capacity).
// ---------------------------------------------------------------------------
__device__ __forceinline__ void gbar2(unsigned* __restrict__ flags, int bid,
                                      unsigned target) {
  __syncthreads();
  if (threadIdx.x == 0) {
    __builtin_amdgcn_fence(__ATOMIC_RELEASE, "agent");
    __hip_atomic_store(flags + bid, target, __ATOMIC_RELAXED,
                       __HIP_MEMORY_SCOPE_AGENT);
  }
  if (threadIdx.x < 64) {
    const int l = threadIdx.x;
    for (;;) {
      unsigned f0 = __hip_atomic_load(flags + l, __ATOMIC_RELAXED, __HIP_MEMORY_SCOPE_AGENT);
      unsigned f1 = __hip_atomic_load(flags + l + 64, __ATOMIC_RELAXED, __HIP_MEMORY_SCOPE_AGENT);
      unsigned f2 = __hip_atomic_load(flags + l + 128, __ATOMIC_RELAXED, __HIP_MEMORY_SCOPE_AGENT);
      unsigned f3 = __hip_atomic_load(flags + l + 192, __ATOMIC_RELAXED, __HIP_MEMORY_SCOPE_AGENT);
      bool ok = (f0 >= target) & (f1 >= target) & (f2 >= target) & (f3 >= target);
      if (__all(ok)) break;
      __builtin_amdgcn_s_sleep(2);
    }
  }
  __syncthreads();
  __builtin_amdgcn_fence(__ATOMIC_ACQUIRE, "agent");
}

// ---------------------------------------------------------------------------
// Convert inputs to bf16 hi/lo planes, permuting rows (b*256+t) -> (t*64+b).
// ---------------------------------------------------------------------------
__global__ __launch_bounds__(256) void convert_a(const float* __restrict__ inp,
                                                 unsigned short* __restrict__ Ah,
                                                 unsigned short* __restrict__ Al) {
  const int i = blockIdx.x;
  const int r = ((i & 255) << 6) + (i >> 8);
  const float* src = inp + (size_t)i * KDIM;
  unsigned short* dh = Ah + (size_t)r * KDIM;
  unsigned short* dl = Al + (size_t)r * KDIM;
  const int base = threadIdx.x * 8;
  float4 v0 = *(const float4*)(src + base);
  float4 v1 = *(const float4*)(src + base + 4);
  float f[8] = {v0.x, v0.y, v0.z, v0.w, v1.x, v1.y, v1.z, v1.w};
  unsigned short h[8], l[8];
  #pragma unroll
  for (int j = 0; j < 8; ++j) {
    unsigned short hb = f2bf(f[j]);
    h[j] = hb;
    l[j] = f2bf(f[j] - bf2f(hb));
  }
  *(bf16x8*)(dh + base) = *(bf16x8*)h;
  *(bf16x8*)(dl + base) = *(bf16x8*)l;
}

// ---------------------------------------------------------------------------
// Transpose + convert M (2048x2048) into M^T bf16 hi/lo: Bt[n][k] = M[k][n].
// ---------------------------------------------------------------------------
__global__ __launch_bounds__(256) void convert_bt(const float* __restrict__ M,
                                                  unsigned short* __restrict__ Bh,
                                                  unsigned short* __restrict__ Bl) {
  __shared__ float t[64][65];
  const int k0 = blockIdx.y * 64, nn0 = blockIdx.x * 64;
  const int tid = threadIdx.x;
  #pragma unroll
  for (int j = 0; j < 4; ++j) {
    int idx = tid + j * 256;
    int r = idx >> 4, c4 = (idx & 15) * 4;
    float4 v = *(const float4*)(M + (size_t)(k0 + r) * KDIM + nn0 + c4);
    t[r][c4 + 0] = v.x; t[r][c4 + 1] = v.y; t[r][c4 + 2] = v.z; t[r][c4 + 3] = v.w;
  }
  __syncthreads();
  #pragma unroll
  for (int j = 0; j < 4; ++j) {
    int idx = tid + j * 256;
    int n = idx >> 4, ks = (idx & 15) * 4;
    unsigned short hh[4], ll[4];
    #pragma unroll
    for (int q = 0; q < 4; ++q) {
      float x = t[ks + q][n];
      unsigned short hb = f2bf(x);
      hh[q] = hb;
      ll[q] = f2bf(x - bf2f(hb));
    }
    *(ushort4*)(Bh + (size_t)(nn0 + n) * KDIM + k0 + ks) = *(ushort4*)hh;
    *(ushort4*)(Bl + (size_t)(nn0 + n) * KDIM + k0 + ks) = *(ushort4*)ll;
  }
}

// ---------------------------------------------------------------------------
// bf16x3-split MFMA GEMM for Ux.
// ---------------------------------------------------------------------------
__global__ __launch_bounds__(256) void gemm_mfma3(const unsigned short* __restrict__ Ah,
                                                  const unsigned short* __restrict__ Al,
                                                  const unsigned short* __restrict__ Bh,
                                                  const unsigned short* __restrict__ Bl,
                                                  float* __restrict__ C) {
  __shared__ unsigned char LAh[8192], LAl[8192], LBh[8192], LBl[8192];
  const int tid = threadIdx.x;
  const int lane = tid & 63;
  const int w = tid >> 6;
  const int wr = w >> 1, wc = w & 1;
  const int m0 = blockIdx.x * 128;
  const int n0 = blockIdx.y * 128;

  f32x4 acc[4][4] = {};

  for (int k0 = 0; k0 < KDIM; k0 += 32) {
    #pragma unroll
    for (int j = 0; j < 2; ++j) {
      int c = j * 256 + tid;
      int row = c >> 2;
      int sp = (c & 3) ^ (row & 3);
      size_t aoff = (size_t)(m0 + row) * KDIM + k0 + sp * 8;
      size_t boff = (size_t)(n0 + row) * KDIM + k0 + sp * 8;
      int ldsb = (j * 256 + w * 64) * 16;
      gload16(Ah + aoff, LAh + ldsb);
      gload16(Al + aoff, LAl + ldsb);
      gload16(Bh + boff, LBh + ldsb);
      gload16(Bl + boff, LBl + ldsb);
    }
    __syncthreads();
    bf16x8 ah[4], al[4], bh[4], bl[4];
    #pragma unroll
    for (int i = 0; i < 4; ++i) {
      int arow = wr * 64 + i * 16 + (lane & 15);
      int abyte = arow * 64 + (((lane >> 4) ^ (arow & 3)) * 16);
      ah[i] = *(const bf16x8*)(LAh + abyte);
      al[i] = *(const bf16x8*)(LAl + abyte);
      int brow = wc * 64 + i * 16 + (lane & 15);
      int bbyte = brow * 64 + (((lane >> 4) ^ (brow & 3)) * 16);
      bh[i] = *(const bf16x8*)(LBh + bbyte);
      bl[i] = *(const bf16x8*)(LBl + bbyte);
    }
    #pragma unroll
    for (int i = 0; i < 4; ++i)
      #pragma unroll
      for (int jn = 0; jn < 4; ++jn) {
        acc[i][jn] = __builtin_amdgcn_mfma_f32_16x16x32_bf16(ah[i], bh[jn], acc[i][jn], 0, 0, 0);
        acc[i][jn] = __builtin_amdgcn_mfma_f32_16x16x32_bf16(ah[i], bl[jn], acc[i][jn], 0, 0, 0);
        acc[i][jn] = __builtin_amdgcn_mfma_f32_16x16x32_bf16(al[i], bh[jn], acc[i][jn], 0, 0, 0);
      }
    __syncthreads();
  }
  #pragma unroll
  for (int i = 0; i < 4; ++i) {
    int grow = m0 + wr * 64 + i * 16 + ((lane >> 4) << 2);
    #pragma unroll
    for (int jn = 0; jn < 4; ++jn) {
      int gcol = n0 + wc * 64 + jn * 16 + (lane & 15);
      #pragma unroll
      for (int r = 0; r < 4; ++r)
        C[(size_t)(grow + r) * KDIM + gcol] = acc[i][jn][r];
    }
  }
}

// ---------------------------------------------------------------------------
// Mobius epilogue for the big GEMM (in-place on Mx -> Ux). One block per row.
// ---------------------------------------------------------------------------
__global__ __launch_bounds__(256) void ux_epilogue(const float* __restrict__ inp,
                                                   float* __restrict__ Mx) {
  const int r = blockIdx.x;
  const int t = r >> 6, b = r & 63;
  const float* xrow = inp + ((size_t)(b * T_DIM + t)) * KDIM;
  float* mrow = Mx + (size_t)r * KDIM;
  const int tid = threadIdx.x;
  __shared__ float lds[8];
  float xs2 = 0.f, ms2 = 0.f;
  float m[8];
  #pragma unroll
  for (int j = 0; j < 8; ++j) {
    const int col = tid + j * 256;
    float xv = xrow[col] + EPSF;
    xs2 += xv * xv;
    float mv = mrow[col];
    m[j] = mv;
    ms2 += mv * mv;
  }
  block_reduce2(xs2, ms2, lds);
  float xn = sqrtf(xs2);
  float mnr = sqrtf(ms2);
  float mxn = mnr + EPSF;
  float s = tanhf((mxn / xn) * atanh_ref(xn)) / mxn;
  float na = s * mnr;
  float pf = fminf(1.0f, MAXN / fmaxf(na, EPSF));
  float sc = s * pf;
  #pragma unroll
  for (int j = 0; j < 8; ++j)
    mrow[tid + j * 256] = m[j] * sc;
}

// ---------------------------------------------------------------------------
// Init for the persistent scan: h = 0+EPS (bf16 hi/lo), hn2 partials (parity 0),
// bvbv scalar, flag vector.
// ---------------------------------------------------------------------------
__global__ __launch_bounds__(256) void scan_init(unsigned short* __restrict__ hh_,
                                                 unsigned short* __restrict__ hl_,
                                                 float* __restrict__ pd,
                                                 const float* __restrict__ bvec,
                                                 float* __restrict__ bvbvp,
                                                 unsigned* __restrict__ flags) {
  const int bx = blockIdx.x;  // 64 blocks
  const int tid = threadIdx.x;
  const unsigned short he = f2bf(EPSF);
  const unsigned short le = f2bf(EPSF - bf2f(he));
  #pragma unroll
  for (int j = 0; j < 8; ++j) {
    int c = tid + j * 256;
    hh_[(size_t)bx * KDIM + c] = he;
    hl_[(size_t)bx * KDIM + c] = le;
  }
  if (bx == 0) {
    for (int i = tid; i < 8192; i += 256) {
      int rg = i >> 12, rem = i & 4095, cs = rem >> 5, rr = rem & 31;
      pd[(((size_t)rg * 128 + cs) * 32 + rr) * 8 + 5] = 16.0f * EPSF * EPSF;
    }
    flags[tid] = 0u;  // NBLK == 256 == blockDim
  }
  if (bx == 1) {
    __shared__ float lds[8];
    float s = 0.f;
    #pragma unroll
    for (int j = 0; j < 8; ++j) {
      float v = bvec[tid + j * 256] + EPSF;
      s += v * v;
    }
    float dummy = 0.f;
    block_reduce2(s, dummy, lds);
    if (tid == 0) *bvbvp = s;
  }
}

// ---------------------------------------------------------------------------
// Persistent whole-scan kernel. 256 blocks x 256 threads.
// Block: rowgroup rg (32 batch rows) x colslice cs (16 cols), XCD-swizzled.
// Per step: bf16x3 MFMA Mh tile -> dot partials -> gbar2 -> reduce + scalar
// chain -> h/out write -> gbar2. Flag-vector barriers (relaxed polling).
// ---------------------------------------------------------------------------
__global__ __launch_bounds__(256) void scan_coop(const unsigned short* __restrict__ Wth,
                                                 const unsigned short* __restrict__ Wtl,
                                                 unsigned short* __restrict__ hh_,
                                                 unsigned short* __restrict__ hl_,
                                                 const float* __restrict__ Ux,
                                                 const float* __restrict__ bvec,
                                                 float* __restrict__ pd,
                                                 const float* __restrict__ bvbvp,
                                                 unsigned* __restrict__ flags,
                                                 float* __restrict__ out) {
  const int tid = threadIdx.x;
  const int bx = blockIdx.x;
  const int lane = tid & 63;
  const int w = tid >> 6;
  const int rg = bx >> 7;                       // 0..1 (32 rows each)
  const int cs = (bx & 7) * 16 + ((bx >> 3) & 15);  // 0..127, XCD-grouped
  const int gc0 = cs * 16;
  const int r = tid >> 3;                       // row within 32
  const int b = rg * 32 + r;                    // batch row
  const int gc = gc0 + (tid & 7) * 2;           // global col (pair)

  __shared__ float wtmp[4][32][16];
  __shared__ float MhL[32][16];
  __shared__ float red[32][6];
  __shared__ float cf[32][3];

  const float bvbv = *bvbvp;
  const float bv0 = bvec[gc] + EPSF;
  const float bv1 = bvec[gc + 1] + EPSF;

  const int arow0 = (rg * 32 + (lane & 15)) * KDIM;
  const int arow1 = (rg * 32 + 16 + (lane & 15)) * KDIM;
  const int brow = (gc0 + (lane & 15)) * KDIM;
  const int ksub = w * 512 + (lane >> 4) * 8;

  for (int t = 0; t < T_DIM; ++t) {
    // ---- phase A: Mh tile (32x16) via bf16x3 MFMA, wave-split-K ----
    f32x4 acc0 = {}, acc1 = {};
    #pragma unroll 4
    for (int ks = 0; ks < 16; ++ks) {
      const int k0 = ksub + ks * 32;
      bf16x8 a0h = *(const bf16x8*)(hh_ + arow0 + k0);
      bf16x8 a0l = *(const bf16x8*)(hl_ + arow0 + k0);
      bf16x8 a1h = *(const bf16x8*)(hh_ + arow1 + k0);
      bf16x8 a1l = *(const bf16x8*)(hl_ + arow1 + k0);
      bf16x8 bh = *(const bf16x8*)(Wth + brow + k0);
      bf16x8 bl = *(const bf16x8*)(Wtl + brow + k0);
      acc0 = __builtin_amdgcn_mfma_f32_16x16x32_bf16(a0h, bh, acc0, 0, 0, 0);
      acc0 = __builtin_amdgcn_mfma_f32_16x16x32_bf16(a0h, bl, acc0, 0, 0, 0);
      acc0 = __builtin_amdgcn_mfma_f32_16x16x32_bf16(a0l, bh, acc0, 0, 0, 0);
      acc1 = __builtin_amdgcn_mfma_f32_16x16x32_bf16(a1h, bh, acc1, 0, 0, 0);
      acc1 = __builtin_amdgcn_mfma_f32_16x16x32_bf16(a1h, bl, acc1, 0, 0, 0);
      acc1 = __builtin_amdgcn_mfma_f32_16x16x32_bf16(a1l, bh, acc1, 0, 0, 0);
    }
    #pragma unroll
    for (int q = 0; q < 4; ++q) {
      wtmp[w][(lane >> 4) * 4 + q][lane & 15] = acc0[q];
      wtmp[w][16 + (lane >> 4) * 4 + q][lane & 15] = acc1[q];
    }
    __syncthreads();
    #pragma unroll
    for (int e = tid; e < 512; e += 256) {
      int rr = e >> 4, cc = e & 15;
      MhL[rr][cc] = wtmp[0][rr][cc] + wtmp[1][rr][cc] + wtmp[2][rr][cc] + wtmp[3][rr][cc];
    }
    __syncthreads();
    const float mh0 = MhL[r][(tid & 7) * 2];
    const float mh1 = MhL[r][(tid & 7) * 2 + 1];
    const float ux0 = __builtin_nontemporal_load(Ux + ((size_t)t * 64 + b) * KDIM + gc) + EPSF;
    const float ux1 = __builtin_nontemporal_load(Ux + ((size_t)t * 64 + b) * KDIM + gc + 1) + EPSF;
    float dt0 = mh0 * mh0 + mh1 * mh1;
    float dt1 = mh0 * ux0 + mh1 * ux1;
    float dt2 = ux0 * ux0 + ux1 * ux1;
    float dt3 = mh0 * bv0 + mh1 * bv1;
    float dt4 = ux0 * bv0 + ux1 * bv1;
    #pragma unroll
    for (int off = 4; off > 0; off >>= 1) {
      dt0 += __shfl_down(dt0, off, 8);
      dt1 += __shfl_down(dt1, off, 8);
      dt2 += __shfl_down(dt2, off, 8);
      dt3 += __shfl_down(dt3, off, 8);
      dt4 += __shfl_down(dt4, off, 8);
    }
    const int par = t & 1;
    if ((tid & 7) == 0) {
      float* slot = pd + ((((size_t)par * 2 + rg) * 128 + cs) * 32 + r) * 8;
      slot[0] = dt0; slot[1] = dt1; slot[2] = dt2; slot[3] = dt3; slot[4] = dt4;
    }
    gbar2(flags, bx, (unsigned)(2 * t + 1));

    // ---- phase B: reduce partials, scalar chain, elementwise update ----
    if (tid < 192) {
      int rr = tid / 6, v = tid - rr * 6;
      const float* base = pd + (((size_t)par * 2 + rg) * 128) * 256 + rr * 8 + v;
      float s = 0.f;
      for (int q = 0; q < 128; ++q) s += base[q * 256];
      red[rr][v] = s;
    }
    __syncthreads();
    if (tid < 32) {
      const float mn2 = red[tid][0], Mhux = red[tid][1], uxux = red[tid][2];
      const float Mhbv = red[tid][3], uxbv = red[tid][4], hn2 = red[tid][5];
      const float hn = sqrtf(hn2);
      const float mnr = sqrtf(mn2);
      const float mxn = mnr + EPSF;
      const float s = tanhf((mxn / hn) * atanh_ref(hn)) / mxn;
      const float n_a = s * mnr;
      const float pfa = fminf(1.0f, MAXN / fmaxf(n_a, EPSF));
      const float sa = s * pfa;
      const float duv = 2.0f * sa * Mhux;
      const float nv = uxux;
      const float na = sa * sa * mn2;
      const float denom = 1.0f + duv + na * nv;
      const float c1 = (1.0f + duv + nv) / denom;
      const float c2 = (1.0f - na) / denom;
      const float r1n2 = c1 * c1 * na + 2.0f * c1 * c2 * sa * Mhux + c2 * c2 * uxux;
      const float pf1 = fminf(1.0f, MAXN / fmaxf(sqrtf(r1n2), EPSF));
      const float Sr1bv = c1 * sa * Mhbv + c2 * uxbv;
      const float duv2 = 2.0f * pf1 * Sr1bv;
      const float na2 = pf1 * pf1 * r1n2;
      const float denom2 = 1.0f + duv2 + na2 * bvbv;
      const float d1 = (1.0f + duv2 + bvbv) / denom2;
      const float d2 = (1.0f - na2) / denom2;
      const float r2n2 = d1 * d1 * na2 + 2.0f * d1 * d2 * pf1 * Sr1bv + d2 * d2 * bvbv;
      const float pf2 = fminf(1.0f, MAXN / fmaxf(sqrtf(r2n2), EPSF));
      cf[tid][0] = pf2 * d1 * pf1 * c1 * sa;  // K_mh
      cf[tid][1] = pf2 * d1 * pf1 * c2;       // K_ux
      cf[tid][2] = pf2 * d2;                  // K_bv
    }
    __syncthreads();
    const float Km = cf[r][0], Ku = cf[r][1], Kb = cf[r][2];
    const float h0 = Km * mh0 + Ku * ux0 + Kb * bv0;
    const float h1 = Km * mh1 + Ku * ux1 + Kb * bv1;
    __builtin_nontemporal_store(h0, out + ((size_t)b * T_DIM + t) * KDIM + gc);
    __builtin_nontemporal_store(h1, out + ((size_t)b * T_DIM + t) * KDIM + gc + 1);
    const float hp0 = h0 + EPSF, hp1 = h1 + EPSF;
    const unsigned short e0 = f2bf(hp0), e1 = f2bf(hp1);
    ushort2 hhv; hhv.x = e0; hhv.y = e1;
    ushort2 hlv; hlv.x = f2bf(hp0 - bf2f(e0)); hlv.y = f2bf(hp1 - bf2f(e1));
    *(ushort2*)(hh_ + (size_t)b * KDIM + gc) = hhv;
    *(ushort2*)(hl_ + (size_t)b * KDIM + gc) = hlv;
    float hn2p = hp0 * hp0 + hp1 * hp1;
    #pragma unroll
    for (int off = 4; off > 0; off >>= 1) hn2p += __shfl_down(hn2p, off, 8);
    if ((tid & 7) == 0)
      pd[((((size_t)(par ^ 1) * 2 + rg) * 128 + cs) * 32 + r) * 8 + 5] = hn2p;
    gbar2(flags, bx, (unsigned)(2 * t + 2));
  }
}

// ---------------------------------------------------------------------------
// Fallback kernels (small-workspace paths).
// ---------------------------------------------------------------------------
__global__ __launch_bounds__(256) void gemm64_splitk(const float* __restrict__ A,
                                                     size_t arstride,
                                                     const float* __restrict__ Bm,
                                                     float* __restrict__ part) {
  const int n0 = blockIdx.x * 64;
  const int kz = blockIdx.y;
  const int kbeg = kz * 256;
  __shared__ float As[16][68];
  __shared__ float Bs[16][64];
  const int tid = threadIdx.x;
  const int tx = tid & 15, ty = tid >> 4;
  const int ai = tid >> 2, ak = (tid & 3) * 4;
  const int bk = tid >> 4, bn = (tid & 15) * 4;
  const float* Arow = A + (size_t)ai * arstride;
  float acc[4][4] = {};
  for (int kt = 0; kt < 16; ++kt) {
    const int k0 = kbeg + kt * 16;
    float4 av = *(const float4*)(Arow + k0 + ak);
    As[ak + 0][ai] = av.x + EPSF;
    As[ak + 1][ai] = av.y + EPSF;
    As[ak + 2][ai] = av.z + EPSF;
    As[ak + 3][ai] = av.w + EPSF;
    float4 bv = *(const float4*)(Bm + (size_t)(k0 + bk) * KDIM + n0 + bn);
    *(float4*)&Bs[bk][bn] = bv;
    __syncthreads();
    #pragma unroll
    for (int k = 0; k < 16; ++k) {
      float4 a4 = *(const float4*)&As[k][ty * 4];
      float4 b4 = *(const float4*)&Bs[k][tx * 4];
      float a[4] = {a4.x, a4.y, a4.z, a4.w};
      float bb[4] = {b4.x, b4.y, b4.z, b4.w};
      #pragma unroll
      for (int i = 0; i < 4; ++i)
        #pragma unroll
        for (int j = 0; j < 4; ++j)
          acc[i][j] = fmaf(a[i], bb[j], acc[i][j]);
    }
    __syncthreads();
  }
  #pragma unroll
  for (int i = 0; i < 4; ++i) {
    float4 o = make_float4(acc[i][0], acc[i][1], acc[i][2], acc[i][3]);
    *(float4*)(part + ((size_t)kz * 64 + ty * 4 + i) * KDIM + n0 + tx * 4) = o;
  }
}

__global__ __launch_bounds__(256) void mob_from_parts(const float* __restrict__ part,
                                                      const float* __restrict__ xbase,
                                                      size_t xstride,
                                                      float* __restrict__ outrows) {
  const int b = blockIdx.x;
  const int tid = threadIdx.x;
  __shared__ float lds[8];
  const float* xrow = xbase + (size_t)b * xstride;
  float xs2 = 0.f, ms2 = 0.f;
  float m[8];
  #pragma unroll
  for (int j = 0; j < 8; ++j) {
    const int col = tid + j * 256;
    float xv = xrow[col] + EPSF;
    xs2 += xv * xv;
    float mv = 0.f;
    for (int kz = 0; kz < 8; ++kz)
      mv += part[((size_t)kz * 64 + b) * KDIM + col];
    m[j] = mv;
    ms2 += mv * mv;
  }
  block_reduce2(xs2, ms2, lds);
  float xn = sqrtf(xs2);
  float mnr = sqrtf(ms2);
  float mxn = mnr + EPSF;
  float s = tanhf((mxn / xn) * atanh_ref(xn)) / mxn;
  float na = s * mnr;
  float pf = fminf(1.0f, MAXN / fmaxf(na, EPSF));
  float sc = s * pf;
  #pragma unroll
  for (int j = 0; j < 8; ++j)
    outrows[(size_t)b * KDIM + tid + j * 256] = m[j] * sc;
}

__global__ __launch_bounds__(256) void step_mobius(const float* __restrict__ part,
                                                   float* __restrict__ h,
                                                   const float* __restrict__ uxrows,
                                                   const float* __restrict__ bvec,
                                                   float* __restrict__ out,
                                                   int t) {
  const int b = blockIdx.x;
  const int tid = threadIdx.x;
  __shared__ float lds[8];
  float mh[8], uxv[8], bv[8];
  float hn2 = 0.f, mn2 = 0.f;
  #pragma unroll
  for (int j = 0; j < 8; ++j) {
    const int col = tid + j * 256;
    float x = h[(size_t)b * KDIM + col] + EPSF;
    hn2 += x * x;
    float m = 0.f;
    for (int kz = 0; kz < 8; ++kz)
      m += part[((size_t)kz * 64 + b) * KDIM + col];
    mh[j] = m;
    mn2 += m * m;
    uxv[j] = uxrows[(size_t)b * KDIM + col] + EPSF;
    bv[j] = bvec[col] + EPSF;
  }
  block_reduce2(hn2, mn2, lds);
  float hn = sqrtf(hn2);
  float mnr = sqrtf(mn2);
  float mxn = mnr + EPSF;
  float s = tanhf((mxn / hn) * atanh_ref(hn)) / mxn;
  float n_a = s * mnr;
  float pfa = fminf(1.0f, MAXN / fmaxf(n_a, EPSF));
  float sa = s * pfa;
  float a[8];
  float duv = 0.f, nv = 0.f;
  #pragma unroll
  for (int j = 0; j < 8; ++j) {
    a[j] = sa * mh[j];
    duv += a[j] * uxv[j];
    nv += uxv[j] * uxv[j];
  }
  block_reduce2(duv, nv, lds);
  duv *= 2.0f;
  float na = sa * sa * mn2;
  float denom = 1.0f + duv + na * nv;
  float c1 = (1.0f + duv + nv) / denom;
  float c2 = (1.0f - na) / denom;
  float r1[8];
  float r1n2 = 0.f, dummy = 0.f;
  #pragma unroll
  for (int j = 0; j < 8; ++j) {
    r1[j] = c1 * a[j] + c2 * uxv[j];
    r1n2 += r1[j] * r1[j];
  }
  block_reduce2(r1n2, dummy, lds);
  float n1 = sqrtf(r1n2);
  float pf1 = fminf(1.0f, MAXN / fmaxf(n1, EPSF));
  float duv2 = 0.f, nv2 = 0.f;
  #pragma unroll
  for (int j = 0; j < 8; ++j) {
    r1[j] *= pf1;
    duv2 += r1[j] * bv[j];
    nv2 += bv[j] * bv[j];
  }
  block_reduce2(duv2, nv2, lds);
  duv2 *= 2.0f;
  float na2 = pf1 * pf1 * r1n2;
  float denom2 = 1.0f + duv2 + na2 * nv2;
  float d1 = (1.0f + duv2 + nv2) / denom2;
  float d2 = (1.0f - na2) / denom2;
  float r2[8];
  float r2n2 = 0.f;
  dummy = 0.f;
  #pragma unroll
  for (int j = 0; j < 8; ++j) {
    r2[j] = d1 * r1[j] + d2 * bv[j];
    r2n2 += r2[j] * r2[j];
  }
  block_reduce2(r2n2, dummy, lds);
  float n2 = sqrtf(r2n2);
  float pf2 = fminf(1.0f, MAXN / fmaxf(n2, EPSF));
  #pragma unroll
  for (int j = 0; j < 8; ++j) {
    const int col = tid + j * 256;
    float vout = r2[j] * pf2;
    h[(size_t)b * KDIM + col] = vout;
    out[((size_t)b * T_DIM + t) * KDIM + col] = vout;
  }
}

extern "C" void kernel_launch(void* const* d_in, const int* in_sizes, int n_in,
                              void* d_out, int out_size, void* d_ws, size_t ws_size,
                              hipStream_t stream) {
  const float* inp  = (const float*)d_in[0];
  const float* wm   = (const float*)d_in[1];
  const float* um   = (const float*)d_in[2];
  const float* bvec = (const float*)d_in[3];
  float* out = (float*)d_out;
  char* ws = (char*)d_ws;

  const size_t UXB  = (size_t)TBROWS * KDIM * 4;   // 134.2 MB
  const size_t AHL  = (size_t)TBROWS * KDIM * 2;   // 67.1 MB
  const size_t BTB  = (size_t)KDIM * KDIM * 2;     // 8.4 MB
  const size_t HB16 = (size_t)B_DIM * KDIM * 2;    // 256 KB
  const size_t PDB  = (size_t)2 * 2 * 128 * 32 * 8 * 4;  // 2 MB
  const size_t META = 2048;                        // bvbv + 256 flags
  const size_t HFP  = (size_t)B_DIM * KDIM * 4;    // 512 KB
  const size_t PART = (size_t)8 * B_DIM * KDIM * 4; // 4 MB

  size_t off = 0;
  float* Ux = (float*)(ws + off); off += UXB;
  unsigned short* Ah = (unsigned short*)(ws + off); off += AHL;
  unsigned short* Al = (unsigned short*)(ws + off); off += AHL;
  unsigned short* Bh = (unsigned short*)(ws + off); off += BTB;
  unsigned short* Bl = (unsigned short*)(ws + off); off += BTB;
  unsigned short* Wth = (unsigned short*)(ws + off); off += BTB;
  unsigned short* Wtl = (unsigned short*)(ws + off); off += BTB;
  unsigned short* hh = (unsigned short*)(ws + off); off += HB16;
  unsigned short* hl = (unsigned short*)(ws + off); off += HB16;
  float* pd = (float*)(ws + off); off += PDB;
  float* bvbvp = (float*)(ws + off);
  unsigned* flagsp = (unsigned*)(ws + off + 128); off += META;
  float* hfp = (float*)(ws + off); off += HFP;
  float* part = (float*)(ws + off); off += PART;
  const size_t NEED_COOP = off;
  const size_t NEED_MFMA = UXB + 2 * AHL + 2 * BTB + HFP + PART;
  const size_t NEED_FP32 = UXB + HFP + PART;

  if (ws_size >= NEED_COOP) {
    convert_a<<<TBROWS, 256, 0, stream>>>(inp, Ah, Al);
    convert_bt<<<dim3(32, 32), 256, 0, stream>>>(um, Bh, Bl);
    convert_bt<<<dim3(32, 32), 256, 0, stream>>>(wm, Wth, Wtl);
    scan_init<<<B_DIM, 256, 0, stream>>>(hh, hl, pd, bvec, bvbvp, flagsp);
    gemm_mfma3<<<dim3(128, 16), 256, 0, stream>>>(Ah, Al, Bh, Bl, Ux);
    ux_epilogue<<<TBROWS, 256, 0, stream>>>(inp, Ux);
    scan_coop<<<NBLK, 256, 0, stream>>>(Wth, Wtl, hh, hl, Ux, bvec, pd, bvbvp,
                                        flagsp, out);
  } else if (ws_size >= NEED_MFMA) {
    float* Ux2 = (float*)ws;
    unsigned short* Ah2 = (unsigned short*)(ws + UXB);
    unsigned short* Al2 = (unsigned short*)(ws + UXB + AHL);
    unsigned short* Bh2 = (unsigned short*)(ws + UXB + 2 * AHL);
    unsigned short* Bl2 = (unsigned short*)(ws + UXB + 2 * AHL + BTB);
    float* h2 = (float*)(ws + UXB + 2 * AHL + 2 * BTB);
    float* part2 = (float*)(ws + UXB + 2 * AHL + 2 * BTB + HFP);
    hipMemsetAsync(h2, 0, HFP, stream);
    convert_a<<<TBROWS, 256, 0, stream>>>(inp, Ah2, Al2);
    convert_bt<<<dim3(32, 32), 256, 0, stream>>>(um, Bh2, Bl2);
    gemm_mfma3<<<dim3(128, 16), 256, 0, stream>>>(Ah2, Al2, Bh2, Bl2, Ux2);
    ux_epilogue<<<TBROWS, 256, 0, stream>>>(inp, Ux2);
    for (int t = 0; t < T_DIM; ++t) {
      gemm64_splitk<<<dim3(32, 8), 256, 0, stream>>>(h2, (size_t)KDIM, wm, part2);
      step_mobius<<<B_DIM, 256, 0, stream>>>(part2, h2, Ux2 + (size_t)t * B_DIM * KDIM,
                                             bvec, out, t);
    }
  } else {
    float* h2 = (float*)ws;
    float* part2 = (float*)(ws + HFP);
    float* partU = (float*)(ws + HFP + PART);
    float* uxstep = (float*)(ws + HFP + 2 * PART);
    hipMemsetAsync(h2, 0, HFP, stream);
    for (int t = 0; t < T_DIM; ++t) {
      const float* xt = inp + (size_t)t * KDIM;
      gemm64_splitk<<<dim3(32, 8), 256, 0, stream>>>(xt, (size_t)T_DIM * KDIM, um, partU);
      mob_from_parts<<<B_DIM, 256, 0, stream>>>(partU, xt, (size_t)T_DIM * KDIM, uxstep);
      gemm64_splitk<<<dim3(32, 8), 256, 0, stream>>>(h2, (size_t)KDIM, wm, part2);
      step_mobius<<<B_DIM, 256, 0, stream>>>(part2, h2, uxstep, bvec, out, t);
    }
  }
}

// Round 7
// 6841.937 us; speedup vs baseline: 3.8730x; 1.9519x over previous
//
#include <hip/hip_runtime.h>
#include <math.h>

#define T_DIM 256
#define B_DIM 64
#define KDIM 2048   // I*D == H*D
#define TBROWS 16384
#define NBLK 256    // persistent scan grid

constexpr float EPSF = 1e-15f;
constexpr float MAXN = 1.0f - 1e-5f;

typedef short bf16x8 __attribute__((ext_vector_type(8)));
typedef float f32x4 __attribute__((ext_vector_type(4)));
typedef unsigned int uint32x4 __attribute__((ext_vector_type(4)));

__device__ __forceinline__ float atanh_ref(float x) {
  x = fminf(x, 1.0f - EPSF);
  return 0.5f * (log1pf(x + EPSF) - log1pf(EPSF - x));
}

__device__ __forceinline__ unsigned short f2bf(float x) {
  unsigned int u = __float_as_uint(x);
  unsigned int r = (u + 0x7fffu + ((u >> 16) & 1u)) >> 16;
  return (unsigned short)r;
}
__device__ __forceinline__ float bf2f(unsigned short h) {
  return __uint_as_float(((unsigned int)h) << 16);
}

__device__ __forceinline__ void gload16(const void* g, void* l) {
  __builtin_amdgcn_global_load_lds(
      (const __attribute__((address_space(1))) unsigned int*)g,
      (__attribute__((address_space(3))) unsigned int*)l, 16, 0, 0);
}

// ---- explicit MALL-coherent (write-through / read-through) accessors ------
// sc0+sc1 = system scope on gfx940+: bypasses L1 and (non-coherent) L2.
// 16B read-through load; caller MUST s_waitcnt vmcnt(0) before using result.
__device__ __forceinline__ uint32x4 ldg_sc16(const void* p) {
  uint32x4 r;
  asm volatile("global_load_dwordx4 %0, %1, off sc0 sc1" : "=v"(r) : "v"(p));
  return r;
}
// 4B read-through load with fused wait (safe standalone).
__device__ __forceinline__ unsigned ldg_sc4_wait(const void* p) {
  unsigned r;
  asm volatile("global_load_dword %0, %1, off sc0 sc1\n\ts_waitcnt vmcnt(0)"
               : "=v"(r) : "v"(p) : "memory");
  return r;
}
// 4B write-through store. NOTE: INVISIBLE to the compiler's waitcnt pass —
// any ordering against it must use an explicit asm s_waitcnt vmcnt(0).
__device__ __forceinline__ void stg_sc4(void* p, unsigned v) {
  asm volatile("global_store_dword %0, %1, off sc0 sc1" :: "v"(p), "v"(v) : "memory");
}
// Drain ALL outstanding VMEM of this wave (hardware counter covers inline-asm
// ops the compiler cannot see).
__device__ __forceinline__ void drain_vmem() {
  asm volatile("s_waitcnt vmcnt(0)" ::: "memory");
}
__device__ __forceinline__ bf16x8 as_bf(uint32x4 x) {
  return __builtin_bit_cast(bf16x8, x);
}

// reduce two values across a 256-thread block; result broadcast to all threads
__device__ __forceinline__ void block_reduce2(float& v0, float& v1, float* lds) {
  #pragma unroll
  for (int off = 32; off > 0; off >>= 1) {
    v0 += __shfl_down(v0, off, 64);
    v1 += __shfl_down(v1, off, 64);
  }
  const int lane = threadIdx.x & 63;
  const int wid  = threadIdx.x >> 6;
  if (lane == 0) { lds[wid * 2] = v0; lds[wid * 2 + 1] = v1; }
  __syncthreads();
  if (threadIdx.x == 0) {
    float s0 = 0.f, s1 = 0.f;
    #pragma unroll
    for (int w = 0; w < 4; ++w) { s0 += lds[w * 2]; s1 += lds[w * 2 + 1]; }
    lds[0] = s0; lds[1] = s1;
  }
  __syncthreads();
  v0 = lds[0]; v1 = lds[1];
  __syncthreads();
}

// ---------------------------------------------------------------------------
// Fence-free 128-block barrier (per rg half). ROUND-6 BUG FIX: the compiler's
// waitcnt pass cannot see inline-asm sc-stores, so __syncthreads() alone does
// NOT drain them — the flag store could overtake the data stores at MALL.
// Explicit per-wave drain_vmem() BEFORE __syncthreads() closes the race:
// all waves drained -> flag set -> pollers that see the flag are guaranteed
// the data is at MALL. Reads after the barrier are sc read-through, so no
// acquire fence (and no L2 invalidation) is needed.
// ---------------------------------------------------------------------------
__device__ __forceinline__ void gbar3(unsigned* __restrict__ flags, int rg,
                                      int ci, unsigned target) {
  drain_vmem();     // covers asm sc-stores + everything else of this wave
  __syncthreads();  // all waves of the block have drained
  if (threadIdx.x == 0)
    stg_sc4(flags + rg * 128 + ci, target);
  if (threadIdx.x < 64) {
    const unsigned* p0 = flags + rg * 128 + threadIdx.x;
    const unsigned* p1 = p0 + 64;
    for (;;) {
      unsigned f0, f1;
      asm volatile("global_load_dword %0, %2, off sc0 sc1\n\t"
                   "global_load_dword %1, %3, off sc0 sc1\n\t"
                   "s_waitcnt vmcnt(0)"
                   : "=v"(f0), "=v"(f1) : "v"(p0), "v"(p1) : "memory");
      if (__all((f0 >= target) & (f1 >= target))) break;
      __builtin_amdgcn_s_sleep(2);
    }
  }
  __syncthreads();
}

// ---------------------------------------------------------------------------
// Convert inputs to bf16 hi/lo planes, permuting rows (b*256+t) -> (t*64+b).
// ---------------------------------------------------------------------------
__global__ __launch_bounds__(256) void convert_a(const float* __restrict__ inp,
                                                 unsigned short* __restrict__ Ah,
                                                 unsigned short* __restrict__ Al) {
  const int i = blockIdx.x;
  const int r = ((i & 255) << 6) + (i >> 8);
  const float* src = inp + (size_t)i * KDIM;
  unsigned short* dh = Ah + (size_t)r * KDIM;
  unsigned short* dl = Al + (size_t)r * KDIM;
  const int base = threadIdx.x * 8;
  float4 v0 = *(const float4*)(src + base);
  float4 v1 = *(const float4*)(src + base + 4);
  float f[8] = {v0.x, v0.y, v0.z, v0.w, v1.x, v1.y, v1.z, v1.w};
  unsigned short h[8], l[8];
  #pragma unroll
  for (int j = 0; j < 8; ++j) {
    unsigned short hb = f2bf(f[j]);
    h[j] = hb;
    l[j] = f2bf(f[j] - bf2f(hb));
  }
  *(bf16x8*)(dh + base) = *(bf16x8*)h;
  *(bf16x8*)(dl + base) = *(bf16x8*)l;
}

// ---------------------------------------------------------------------------
// Transpose + convert M (2048x2048) into M^T bf16 hi/lo: Bt[n][k] = M[k][n].
// ---------------------------------------------------------------------------
__global__ __launch_bounds__(256) void convert_bt(const float* __restrict__ M,
                                                  unsigned short* __restrict__ Bh,
                                                  unsigned short* __restrict__ Bl) {
  __shared__ float t[64][65];
  const int k0 = blockIdx.y * 64, nn0 = blockIdx.x * 64;
  const int tid = threadIdx.x;
  #pragma unroll
  for (int j = 0; j < 4; ++j) {
    int idx = tid + j * 256;
    int r = idx >> 4, c4 = (idx & 15) * 4;
    float4 v = *(const float4*)(M + (size_t)(k0 + r) * KDIM + nn0 + c4);
    t[r][c4 + 0] = v.x; t[r][c4 + 1] = v.y; t[r][c4 + 2] = v.z; t[r][c4 + 3] = v.w;
  }
  __syncthreads();
  #pragma unroll
  for (int j = 0; j < 4; ++j) {
    int idx = tid + j * 256;
    int n = idx >> 4, ks = (idx & 15) * 4;
    unsigned short hh[4], ll[4];
    #pragma unroll
    for (int q = 0; q < 4; ++q) {
      float x = t[ks + q][n];
      unsigned short hb = f2bf(x);
      hh[q] = hb;
      ll[q] = f2bf(x - bf2f(hb));
    }
    *(ushort4*)(Bh + (size_t)(nn0 + n) * KDIM + k0 + ks) = *(ushort4*)hh;
    *(ushort4*)(Bl + (size_t)(nn0 + n) * KDIM + k0 + ks) = *(ushort4*)ll;
  }
}

// ---------------------------------------------------------------------------
// bf16x3-split MFMA GEMM for Ux.
// ---------------------------------------------------------------------------
__global__ __launch_bounds__(256) void gemm_mfma3(const unsigned short* __restrict__ Ah,
                                                  const unsigned short* __restrict__ Al,
                                                  const unsigned short* __restrict__ Bh,
                                                  const unsigned short* __restrict__ Bl,
                                                  float* __restrict__ C) {
  __shared__ unsigned char LAh[8192], LAl[8192], LBh[8192], LBl[8192];
  const int tid = threadIdx.x;
  const int lane = tid & 63;
  const int w = tid >> 6;
  const int wr = w >> 1, wc = w & 1;
  const int m0 = blockIdx.x * 128;
  const int n0 = blockIdx.y * 128;

  f32x4 acc[4][4] = {};

  for (int k0 = 0; k0 < KDIM; k0 += 32) {
    #pragma unroll
    for (int j = 0; j < 2; ++j) {
      int c = j * 256 + tid;
      int row = c >> 2;
      int sp = (c & 3) ^ (row & 3);
      size_t aoff = (size_t)(m0 + row) * KDIM + k0 + sp * 8;
      size_t boff = (size_t)(n0 + row) * KDIM + k0 + sp * 8;
      int ldsb = (j * 256 + w * 64) * 16;
      gload16(Ah + aoff, LAh + ldsb);
      gload16(Al + aoff, LAl + ldsb);
      gload16(Bh + boff, LBh + ldsb);
      gload16(Bl + boff, LBl + ldsb);
    }
    __syncthreads();
    bf16x8 ah[4], al[4], bh[4], bl[4];
    #pragma unroll
    for (int i = 0; i < 4; ++i) {
      int arow = wr * 64 + i * 16 + (lane & 15);
      int abyte = arow * 64 + (((lane >> 4) ^ (arow & 3)) * 16);
      ah[i] = *(const bf16x8*)(LAh + abyte);
      al[i] = *(const bf16x8*)(LAl + abyte);
      int brow = wc * 64 + i * 16 + (lane & 15);
      int bbyte = brow * 64 + (((lane >> 4) ^ (brow & 3)) * 16);
      bh[i] = *(const bf16x8*)(LBh + bbyte);
      bl[i] = *(const bf16x8*)(LBl + bbyte);
    }
    #pragma unroll
    for (int i = 0; i < 4; ++i)
      #pragma unroll
      for (int jn = 0; jn < 4; ++jn) {
        acc[i][jn] = __builtin_amdgcn_mfma_f32_16x16x32_bf16(ah[i], bh[jn], acc[i][jn], 0, 0, 0);
        acc[i][jn] = __builtin_amdgcn_mfma_f32_16x16x32_bf16(ah[i], bl[jn], acc[i][jn], 0, 0, 0);
        acc[i][jn] = __builtin_amdgcn_mfma_f32_16x16x32_bf16(al[i], bh[jn], acc[i][jn], 0, 0, 0);
      }
    __syncthreads();
  }
  #pragma unroll
  for (int i = 0; i < 4; ++i) {
    int grow = m0 + wr * 64 + i * 16 + ((lane >> 4) << 2);
    #pragma unroll
    for (int jn = 0; jn < 4; ++jn) {
      int gcol = n0 + wc * 64 + jn * 16 + (lane & 15);
      #pragma unroll
      for (int r = 0; r < 4; ++r)
        C[(size_t)(grow + r) * KDIM + gcol] = acc[i][jn][r];
    }
  }
}

// ---------------------------------------------------------------------------
// Mobius epilogue for the big GEMM (in-place on Mx -> Ux). One block per row.
// ---------------------------------------------------------------------------
__global__ __launch_bounds__(256) void ux_epilogue(const float* __restrict__ inp,
                                                   float* __restrict__ Mx) {
  const int r = blockIdx.x;
  const int t = r >> 6, b = r & 63;
  const float* xrow = inp + ((size_t)(b * T_DIM + t)) * KDIM;
  float* mrow = Mx + (size_t)r * KDIM;
  const int tid = threadIdx.x;
  __shared__ float lds[8];
  float xs2 = 0.f, ms2 = 0.f;
  float m[8];
  #pragma unroll
  for (int j = 0; j < 8; ++j) {
    const int col = tid + j * 256;
    float xv = xrow[col] + EPSF;
    xs2 += xv * xv;
    float mv = mrow[col];
    m[j] = mv;
    ms2 += mv * mv;
  }
  block_reduce2(xs2, ms2, lds);
  float xn = sqrtf(xs2);
  float mnr = sqrtf(ms2);
  float mxn = mnr + EPSF;
  float s = tanhf((mxn / xn) * atanh_ref(xn)) / mxn;
  float na = s * mnr;
  float pf = fminf(1.0f, MAXN / fmaxf(na, EPSF));
  float sc = s * pf;
  #pragma unroll
  for (int j = 0; j < 8; ++j)
    mrow[tid + j * 256] = m[j] * sc;
}

// ---------------------------------------------------------------------------
// Init for the persistent scan: h = 0+EPS (bf16 hi/lo), pd accumulators
// (zeroed; parity-0 hn2 = 2048*EPS^2), bvbv scalar, flag vector.
// pd layout: pd[par 0..1][val 0..5][row 0..63]  (val 5 = hn2)
// ---------------------------------------------------------------------------
__global__ __launch_bounds__(256) void scan_init(unsigned short* __restrict__ hh_,
                                                 unsigned short* __restrict__ hl_,
                                                 float* __restrict__ pd,
                                                 const float* __restrict__ bvec,
                                                 float* __restrict__ bvbvp,
                                                 unsigned* __restrict__ flags) {
  const int bx = blockIdx.x;  // 64 blocks
  const int tid = threadIdx.x;
  const unsigned short he = f2bf(EPSF);
  const unsigned short le = f2bf(EPSF - bf2f(he));
  #pragma unroll
  for (int j = 0; j < 8; ++j) {
    int c = tid + j * 256;
    hh_[(size_t)bx * KDIM + c] = he;
    hl_[(size_t)bx * KDIM + c] = le;
  }
  if (bx == 0) {
    for (int i = tid; i < 768; i += 256) {
      bool hn2slot = (i >= 320) && (i < 384);  // par0, val5
      float v = hn2slot ? (2048.0f * EPSF * EPSF) : 0.0f;
      stg_sc4(pd + i, __float_as_uint(v));
    }
    stg_sc4(flags + tid, 0u);  // 256 flags
    drain_vmem();              // asm stores are untracked; drain before endpgm
  }
  if (bx == 1) {
    __shared__ float lds[8];
    float s = 0.f;
    #pragma unroll
    for (int j = 0; j < 8; ++j) {
      float v = bvec[tid + j * 256] + EPSF;
      s += v * v;
    }
    float dummy = 0.f;
    block_reduce2(s, dummy, lds);
    if (tid == 0) *bvbvp = s;
  }
}

// ---------------------------------------------------------------------------
// Persistent whole-scan kernel. 256 blocks x 256 threads, fence-free.
// ALL cross-block traffic is explicit write-through/read-through at MALL:
// h (sc-stores + sc-loads), pd (RMW atomicAdd + sc-loads + sc-zeroing),
// flags (sc-store + sc-poll). W/Ux stay normally cached (never invalidated).
// ---------------------------------------------------------------------------
__global__ __launch_bounds__(256) void scan_coop(const unsigned short* __restrict__ Wth,
                                                 const unsigned short* __restrict__ Wtl,
                                                 unsigned short* __restrict__ hh_,
                                                 unsigned short* __restrict__ hl_,
                                                 const float* __restrict__ Ux,
                                                 const float* __restrict__ bvec,
                                                 float* __restrict__ pd,
                                                 const float* __restrict__ bvbvp,
                                                 unsigned* __restrict__ flags,
                                                 float* __restrict__ out) {
  const int tid = threadIdx.x;
  const int bx = blockIdx.x;
  const int lane = tid & 63;
  const int w = tid >> 6;
  const int rg = bx >> 7;                       // 0..1 (32 rows each)
  const int ci = bx & 127;                      // barrier slot within rg-half
  const int cs = (bx & 7) * 16 + ((bx >> 3) & 15);  // 0..127, XCD-grouped
  const int gc0 = cs * 16;
  const int r = tid >> 3;                       // row within 32
  const int b = rg * 32 + r;                    // batch row
  const int gc = gc0 + (tid & 7) * 2;           // global col (pair)

  __shared__ float wtmp[4][32][16];
  __shared__ float MhL[32][16];
  __shared__ float red[32][6];
  __shared__ float cf[32][3];

  const float bvbv = *bvbvp;
  const float bv0 = bvec[gc] + EPSF;
  const float bv1 = bvec[gc + 1] + EPSF;

  const int arow0 = (rg * 32 + (lane & 15)) * KDIM;
  const int arow1 = (rg * 32 + 16 + (lane & 15)) * KDIM;
  const int brow = (gc0 + (lane & 15)) * KDIM;
  const int ksub = w * 512 + (lane >> 4) * 8;

  for (int t = 0; t < T_DIM; ++t) {
    const int par = t & 1;
    // zero the OTHER parity's accumulators (write-through; readers finished
    // at step t-1 phase B, barrier-separated).
    if (tid < 192) {
      int v = tid >> 5, rr = tid & 31;
      stg_sc4(pd + (((size_t)(par ^ 1) * 6 + v) * 64 + rg * 32 + rr), 0u);
    }

    // ---- phase A: Mh tile (32x16) via bf16x3 MFMA, wave-split-K ----
    f32x4 acc0 = {}, acc1 = {};
    #pragma unroll
    for (int g = 0; g < 4; ++g) {
      uint32x4 xb[16];
      bf16x8 wb[8];
      #pragma unroll
      for (int q = 0; q < 4; ++q) {
        const int kq = ksub + (g * 4 + q) * 32;
        xb[q * 4 + 0] = ldg_sc16(hh_ + arow0 + kq);
        xb[q * 4 + 1] = ldg_sc16(hl_ + arow0 + kq);
        xb[q * 4 + 2] = ldg_sc16(hh_ + arow1 + kq);
        xb[q * 4 + 3] = ldg_sc16(hl_ + arow1 + kq);
        wb[q * 2 + 0] = *(const bf16x8*)(Wth + brow + kq);
        wb[q * 2 + 1] = *(const bf16x8*)(Wtl + brow + kq);
      }
      asm volatile("s_waitcnt vmcnt(0)" ::: "memory");
      __builtin_amdgcn_sched_barrier(0);
      #pragma unroll
      for (int q = 0; q < 4; ++q) {
        bf16x8 a0h = as_bf(xb[q * 4 + 0]);
        bf16x8 a0l = as_bf(xb[q * 4 + 1]);
        bf16x8 a1h = as_bf(xb[q * 4 + 2]);
        bf16x8 a1l = as_bf(xb[q * 4 + 3]);
        bf16x8 bh = wb[q * 2 + 0];
        bf16x8 bl = wb[q * 2 + 1];
        acc0 = __builtin_amdgcn_mfma_f32_16x16x32_bf16(a0h, bh, acc0, 0, 0, 0);
        acc0 = __builtin_amdgcn_mfma_f32_16x16x32_bf16(a0h, bl, acc0, 0, 0, 0);
        acc0 = __builtin_amdgcn_mfma_f32_16x16x32_bf16(a0l, bh, acc0, 0, 0, 0);
        acc1 = __builtin_amdgcn_mfma_f32_16x16x32_bf16(a1h, bh, acc1, 0, 0, 0);
        acc1 = __builtin_amdgcn_mfma_f32_16x16x32_bf16(a1h, bl, acc1, 0, 0, 0);
        acc1 = __builtin_amdgcn_mfma_f32_16x16x32_bf16(a1l, bh, acc1, 0, 0, 0);
      }
    }
    #pragma unroll
    for (int q = 0; q < 4; ++q) {
      wtmp[w][(lane >> 4) * 4 + q][lane & 15] = acc0[q];
      wtmp[w][16 + (lane >> 4) * 4 + q][lane & 15] = acc1[q];
    }
    __syncthreads();
    #pragma unroll
    for (int e = tid; e < 512; e += 256) {
      int rr = e >> 4, cc = e & 15;
      MhL[rr][cc] = wtmp[0][rr][cc] + wtmp[1][rr][cc] + wtmp[2][rr][cc] + wtmp[3][rr][cc];
    }
    __syncthreads();
    const float mh0 = MhL[r][(tid & 7) * 2];
    const float mh1 = MhL[r][(tid & 7) * 2 + 1];
    const float ux0 = __builtin_nontemporal_load(Ux + ((size_t)t * 64 + b) * KDIM + gc) + EPSF;
    const float ux1 = __builtin_nontemporal_load(Ux + ((size_t)t * 64 + b) * KDIM + gc + 1) + EPSF;
    float dt0 = mh0 * mh0 + mh1 * mh1;
    float dt1 = mh0 * ux0 + mh1 * ux1;
    float dt2 = ux0 * ux0 + ux1 * ux1;
    float dt3 = mh0 * bv0 + mh1 * bv1;
    float dt4 = ux0 * bv0 + ux1 * bv1;
    #pragma unroll
    for (int off = 4; off > 0; off >>= 1) {
      dt0 += __shfl_down(dt0, off, 8);
      dt1 += __shfl_down(dt1, off, 8);
      dt2 += __shfl_down(dt2, off, 8);
      dt3 += __shfl_down(dt3, off, 8);
      dt4 += __shfl_down(dt4, off, 8);
    }
    if ((tid & 7) == 0) {
      float dts[5] = {dt0, dt1, dt2, dt3, dt4};
      #pragma unroll
      for (int v = 0; v < 5; ++v)
        __hip_atomic_fetch_add(pd + (((size_t)par * 6 + v) * 64 + b), dts[v],
                               __ATOMIC_RELAXED, __HIP_MEMORY_SCOPE_AGENT);
    }
    gbar3(flags, rg, ci, (unsigned)(2 * t + 1));

    // ---- phase B: read accumulated dots (read-through), scalar chain ----
    if (tid < 192) {
      int v = tid >> 5, rr = tid & 31;
      unsigned u = ldg_sc4_wait(pd + (((size_t)par * 6 + v) * 64 + rg * 32 + rr));
      red[rr][v] = __uint_as_float(u);
    }
    __syncthreads();
    if (tid < 32) {
      const float mn2 = red[tid][0], Mhux = red[tid][1], uxux = red[tid][2];
      const float Mhbv = red[tid][3], uxbv = red[tid][4], hn2 = red[tid][5];
      const float hn = sqrtf(hn2);
      const float mnr = sqrtf(mn2);
      const float mxn = mnr + EPSF;
      const float s = tanhf((mxn / hn) * atanh_ref(hn)) / mxn;
      const float n_a = s * mnr;
      const float pfa = fminf(1.0f, MAXN / fmaxf(n_a, EPSF));
      const float sa = s * pfa;
      const float duv = 2.0f * sa * Mhux;
      const float nv = uxux;
      const float na = sa * sa * mn2;
      const float denom = 1.0f + duv + na * nv;
      const float c1 = (1.0f + duv + nv) / denom;
      const float c2 = (1.0f - na) / denom;
      const float r1n2 = c1 * c1 * na + 2.0f * c1 * c2 * sa * Mhux + c2 * c2 * uxux;
      const float pf1 = fminf(1.0f, MAXN / fmaxf(sqrtf(r1n2), EPSF));
      const float Sr1bv = c1 * sa * Mhbv + c2 * uxbv;
      const float duv2 = 2.0f * pf1 * Sr1bv;
      const float na2 = pf1 * pf1 * r1n2;
      const float denom2 = 1.0f + duv2 + na2 * bvbv;
      const float d1 = (1.0f + duv2 + bvbv) / denom2;
      const float d2 = (1.0f - na2) / denom2;
      const float r2n2 = d1 * d1 * na2 + 2.0f * d1 * d2 * pf1 * Sr1bv + d2 * d2 * bvbv;
      const float pf2 = fminf(1.0f, MAXN / fmaxf(sqrtf(r2n2), EPSF));
      cf[tid][0] = pf2 * d1 * pf1 * c1 * sa;  // K_mh
      cf[tid][1] = pf2 * d1 * pf1 * c2;       // K_ux
      cf[tid][2] = pf2 * d2;                  // K_bv
    }
    __syncthreads();
    const float Km = cf[r][0], Ku = cf[r][1], Kb = cf[r][2];
    const float h0 = Km * mh0 + Ku * ux0 + Kb * bv0;
    const float h1 = Km * mh1 + Ku * ux1 + Kb * bv1;
    __builtin_nontemporal_store(h0, out + ((size_t)b * T_DIM + t) * KDIM + gc);
    __builtin_nontemporal_store(h1, out + ((size_t)b * T_DIM + t) * KDIM + gc + 1);
    const float hp0 = h0 + EPSF, hp1 = h1 + EPSF;
    const unsigned short e0 = f2bf(hp0), e1 = f2bf(hp1);
    const unsigned short l0 = f2bf(hp0 - bf2f(e0)), l1 = f2bf(hp1 - bf2f(e1));
    const unsigned hhu = (unsigned)e0 | ((unsigned)e1 << 16);
    const unsigned hlu = (unsigned)l0 | ((unsigned)l1 << 16);
    stg_sc4(hh_ + (size_t)b * KDIM + gc, hhu);   // write-through to MALL
    stg_sc4(hl_ + (size_t)b * KDIM + gc, hlu);
    float hn2p = hp0 * hp0 + hp1 * hp1;
    #pragma unroll
    for (int off = 4; off > 0; off >>= 1) hn2p += __shfl_down(hn2p, off, 8);
    if ((tid & 7) == 0)
      __hip_atomic_fetch_add(pd + (((size_t)(par ^ 1) * 6 + 5) * 64 + b), hn2p,
                             __ATOMIC_RELAXED, __HIP_MEMORY_SCOPE_AGENT);
    gbar3(flags, rg, ci, (unsigned)(2 * t + 2));
  }
}

// ---------------------------------------------------------------------------
// Fallback kernels (small-workspace paths).
// ---------------------------------------------------------------------------
__global__ __launch_bounds__(256) void gemm64_splitk(const float* __restrict__ A,
                                                     size_t arstride,
                                                     const float* __restrict__ Bm,
                                                     float* __restrict__ part) {
  const int n0 = blockIdx.x * 64;
  const int kz = blockIdx.y;
  const int kbeg = kz * 256;
  __shared__ float As[16][68];
  __shared__ float Bs[16][64];
  const int tid = threadIdx.x;
  const int tx = tid & 15, ty = tid >> 4;
  const int ai = tid >> 2, ak = (tid & 3) * 4;
  const int bk = tid >> 4, bn = (tid & 15) * 4;
  const float* Arow = A + (size_t)ai * arstride;
  float acc[4][4] = {};
  for (int kt = 0; kt < 16; ++kt) {
    const int k0 = kbeg + kt * 16;
    float4 av = *(const float4*)(Arow + k0 + ak);
    As[ak + 0][ai] = av.x + EPSF;
    As[ak + 1][ai] = av.y + EPSF;
    As[ak + 2][ai] = av.z + EPSF;
    As[ak + 3][ai] = av.w + EPSF;
    float4 bv = *(const float4*)(Bm + (size_t)(k0 + bk) * KDIM + n0 + bn);
    *(float4*)&Bs[bk][bn] = bv;
    __syncthreads();
    #pragma unroll
    for (int k = 0; k < 16; ++k) {
      float4 a4 = *(const float4*)&As[k][ty * 4];
      float4 b4 = *(const float4*)&Bs[k][tx * 4];
      float a[4] = {a4.x, a4.y, a4.z, a4.w};
      float bb[4] = {b4.x, b4.y, b4.z, b4.w};
      #pragma unroll
      for (int i = 0; i < 4; ++i)
        #pragma unroll
        for (int j = 0; j < 4; ++j)
          acc[i][j] = fmaf(a[i], bb[j], acc[i][j]);
    }
    __syncthreads();
  }
  #pragma unroll
  for (int i = 0; i < 4; ++i) {
    float4 o = make_float4(acc[i][0], acc[i][1], acc[i][2], acc[i][3]);
    *(float4*)(part + ((size_t)kz * 64 + ty * 4 + i) * KDIM + n0 + tx * 4) = o;
  }
}

__global__ __launch_bounds__(256) void mob_from_parts(const float* __restrict__ part,
                                                      const float* __restrict__ xbase,
                                                      size_t xstride,
                                                      float* __restrict__ outrows) {
  const int b = blockIdx.x;
  const int tid = threadIdx.x;
  __shared__ float lds[8];
  const float* xrow = xbase + (size_t)b * xstride;
  float xs2 = 0.f, ms2 = 0.f;
  float m[8];
  #pragma unroll
  for (int j = 0; j < 8; ++j) {
    const int col = tid + j * 256;
    float xv = xrow[col] + EPSF;
    xs2 += xv * xv;
    float mv = 0.f;
    for (int kz = 0; kz < 8; ++kz)
      mv += part[((size_t)kz * 64 + b) * KDIM + col];
    m[j] = mv;
    ms2 += mv * mv;
  }
  block_reduce2(xs2, ms2, lds);
  float xn = sqrtf(xs2);
  float mnr = sqrtf(ms2);
  float mxn = mnr + EPSF;
  float s = tanhf((mxn / xn) * atanh_ref(xn)) / mxn;
  float na = s * mnr;
  float pf = fminf(1.0f, MAXN / fmaxf(na, EPSF));
  float sc = s * pf;
  #pragma unroll
  for (int j = 0; j < 8; ++j)
    outrows[(size_t)b * KDIM + tid + j * 256] = m[j] * sc;
}

__global__ __launch_bounds__(256) void step_mobius(const float* __restrict__ part,
                                                   float* __restrict__ h,
                                                   const float* __restrict__ uxrows,
                                                   const float* __restrict__ bvec,
                                                   float* __restrict__ out,
                                                   int t) {
  const int b = blockIdx.x;
  const int tid = threadIdx.x;
  __shared__ float lds[8];
  float mh[8], uxv[8], bv[8];
  float hn2 = 0.f, mn2 = 0.f;
  #pragma unroll
  for (int j = 0; j < 8; ++j) {
    const int col = tid + j * 256;
    float x = h[(size_t)b * KDIM + col] + EPSF;
    hn2 += x * x;
    float m = 0.f;
    for (int kz = 0; kz < 8; ++kz)
      m += part[((size_t)kz * 64 + b) * KDIM + col];
    mh[j] = m;
    mn2 += m * m;
    uxv[j] = uxrows[(size_t)b * KDIM + col] + EPSF;
    bv[j] = bvec[col] + EPSF;
  }
  block_reduce2(hn2, mn2, lds);
  float hn = sqrtf(hn2);
  float mnr = sqrtf(mn2);
  float mxn = mnr + EPSF;
  float s = tanhf((mxn / hn) * atanh_ref(hn)) / mxn;
  float n_a = s * mnr;
  float pfa = fminf(1.0f, MAXN / fmaxf(n_a, EPSF));
  float sa = s * pfa;
  float a[8];
  float duv = 0.f, nv = 0.f;
  #pragma unroll
  for (int j = 0; j < 8; ++j) {
    a[j] = sa * mh[j];
    duv += a[j] * uxv[j];
    nv += uxv[j] * uxv[j];
  }
  block_reduce2(duv, nv, lds);
  duv *= 2.0f;
  float na = sa * sa * mn2;
  float denom = 1.0f + duv + na * nv;
  float c1 = (1.0f + duv + nv) / denom;
  float c2 = (1.0f - na) / denom;
  float r1[8];
  float r1n2 = 0.f, dummy = 0.f;
  #pragma unroll
  for (int j = 0; j < 8; ++j) {
    r1[j] = c1 * a[j] + c2 * uxv[j];
    r1n2 += r1[j] * r1[j];
  }
  block_reduce2(r1n2, dummy, lds);
  float n1 = sqrtf(r1n2);
  float pf1 = fminf(1.0f, MAXN / fmaxf(n1, EPSF));
  float duv2 = 0.f, nv2 = 0.f;
  #pragma unroll
  for (int j = 0; j < 8; ++j) {
    r1[j] *= pf1;
    duv2 += r1[j] * bv[j];
    nv2 += bv[j] * bv[j];
  }
  block_reduce2(duv2, nv2, lds);
  duv2 *= 2.0f;
  float na2 = pf1 * pf1 * r1n2;
  float denom2 = 1.0f + duv2 + na2 * nv2;
  float d1 = (1.0f + duv2 + nv2) / denom2;
  float d2 = (1.0f - na2) / denom2;
  float r2[8];
  float r2n2 = 0.f;
  dummy = 0.f;
  #pragma unroll
  for (int j = 0; j < 8; ++j) {
    r2[j] = d1 * r1[j] + d2 * bv[j];
    r2n2 += r2[j] * r2[j];
  }
  block_reduce2(r2n2, dummy, lds);
  float n2 = sqrtf(r2n2);
  float pf2 = fminf(1.0f, MAXN / fmaxf(n2, EPSF));
  #pragma unroll
  for (int j = 0; j < 8; ++j) {
    const int col = tid + j * 256;
    float vout = r2[j] * pf2;
    h[(size_t)b * KDIM + col] = vout;
    out[((size_t)b * T_DIM + t) * KDIM + col] = vout;
  }
}

extern "C" void kernel_launch(void* const* d_in, const int* in_sizes, int n_in,
                              void* d_out, int out_size, void* d_ws, size_t ws_size,
                              hipStream_t stream) {
  const float* inp  = (const float*)d_in[0];
  const float* wm   = (const float*)d_in[1];
  const float* um   = (const float*)d_in[2];
  const float* bvec = (const float*)d_in[3];
  float* out = (float*)d_out;
  char* ws = (char*)d_ws;

  const size_t UXB  = (size_t)TBROWS * KDIM * 4;   // 134.2 MB
  const size_t AHL  = (size_t)TBROWS * KDIM * 2;   // 67.1 MB
  const size_t BTB  = (size_t)KDIM * KDIM * 2;     // 8.4 MB
  const size_t HB16 = (size_t)B_DIM * KDIM * 2;    // 256 KB
  const size_t PDB  = 4096;                        // 2*6*64 floats (+pad)
  const size_t META = 2048;                        // bvbv + 256 flags
  const size_t HFP  = (size_t)B_DIM * KDIM * 4;    // 512 KB
  const size_t PART = (size_t)8 * B_DIM * KDIM * 4; // 4 MB

  size_t off = 0;
  float* Ux = (float*)(ws + off); off += UXB;
  unsigned short* Ah = (unsigned short*)(ws + off); off += AHL;
  unsigned short* Al = (unsigned short*)(ws + off); off += AHL;
  unsigned short* Bh = (unsigned short*)(ws + off); off += BTB;
  unsigned short* Bl = (unsigned short*)(ws + off); off += BTB;
  unsigned short* Wth = (unsigned short*)(ws + off); off += BTB;
  unsigned short* Wtl = (unsigned short*)(ws + off); off += BTB;
  unsigned short* hh = (unsigned short*)(ws + off); off += HB16;
  unsigned short* hl = (unsigned short*)(ws + off); off += HB16;
  float* pd = (float*)(ws + off); off += PDB;
  float* bvbvp = (float*)(ws + off);
  unsigned* flagsp = (unsigned*)(ws + off + 128); off += META;
  float* hfp = (float*)(ws + off); off += HFP;
  float* part = (float*)(ws + off); off += PART;
  const size_t NEED_COOP = off;
  const size_t NEED_MFMA = UXB + 2 * AHL + 2 * BTB + HFP + PART;
  const size_t NEED_FP32 = UXB + HFP + PART;

  if (ws_size >= NEED_COOP) {
    convert_a<<<TBROWS, 256, 0, stream>>>(inp, Ah, Al);
    convert_bt<<<dim3(32, 32), 256, 0, stream>>>(um, Bh, Bl);
    convert_bt<<<dim3(32, 32), 256, 0, stream>>>(wm, Wth, Wtl);
    scan_init<<<B_DIM, 256, 0, stream>>>(hh, hl, pd, bvec, bvbvp, flagsp);
    gemm_mfma3<<<dim3(128, 16), 256, 0, stream>>>(Ah, Al, Bh, Bl, Ux);
    ux_epilogue<<<TBROWS, 256, 0, stream>>>(inp, Ux);
    scan_coop<<<NBLK, 256, 0, stream>>>(Wth, Wtl, hh, hl, Ux, bvec, pd, bvbvp,
                                        flagsp, out);
  } else if (ws_size >= NEED_MFMA) {
    float* Ux2 = (float*)ws;
    unsigned short* Ah2 = (unsigned short*)(ws + UXB);
    unsigned short* Al2 = (unsigned short*)(ws + UXB + AHL);
    unsigned short* Bh2 = (unsigned short*)(ws + UXB + 2 * AHL);
    unsigned short* Bl2 = (unsigned short*)(ws + UXB + 2 * AHL + BTB);
    float* h2 = (float*)(ws + UXB + 2 * AHL + 2 * BTB);
    float* part2 = (float*)(ws + UXB + 2 * AHL + 2 * BTB + HFP);
    hipMemsetAsync(h2, 0, HFP, stream);
    convert_a<<<TBROWS, 256, 0, stream>>>(inp, Ah2, Al2);
    convert_bt<<<dim3(32, 32), 256, 0, stream>>>(um, Bh2, Bl2);
    gemm_mfma3<<<dim3(128, 16), 256, 0, stream>>>(Ah2, Al2, Bh2, Bl2, Ux2);
    ux_epilogue<<<TBROWS, 256, 0, stream>>>(inp, Ux2);
    for (int t = 0; t < T_DIM; ++t) {
      gemm64_splitk<<<dim3(32, 8), 256, 0, stream>>>(h2, (size_t)KDIM, wm, part2);
      step_mobius<<<B_DIM, 256, 0, stream>>>(part2, h2, Ux2 + (size_t)t * B_DIM * KDIM,
                                             bvec, out, t);
    }
  } else {
    float* h2 = (float*)ws;
    float* part2 = (float*)(ws + HFP);
    float* partU = (float*)(ws + HFP + PART);
    float* uxstep = (float*)(ws + HFP + 2 * PART);
    hipMemsetAsync(h2, 0, HFP, stream);
    for (int t = 0; t < T_DIM; ++t) {
      const float* xt = inp + (size_t)t * KDIM;
      gemm64_splitk<<<dim3(32, 8), 256, 0, stream>>>(xt, (size_t)T_DIM * KDIM, um, partU);
      mob_from_parts<<<B_DIM, 256, 0, stream>>>(partU, xt, (size_t)T_DIM * KDIM, uxstep);
      gemm64_splitk<<<dim3(32, 8), 256, 0, stream>>>(h2, (size_t)KDIM, wm, part2);
      step_mobius<<<B_DIM, 256, 0, stream>>>(part2, h2, uxstep, bvec, out, t);
    }
  }
}

// Round 9
// 6559.160 us; speedup vs baseline: 4.0400x; 1.0431x over previous
//
#include <hip/hip_runtime.h>
#include <math.h>

#define T_DIM 256
#define B_DIM 64
#define KDIM 2048   // I*D == H*D
#define TBROWS 16384
#define NBLK 128    // persistent scan grid: 2 rg x 64 col-slices

constexpr float EPSF = 1e-15f;
constexpr float MAXN = 1.0f - 1e-5f;

typedef short bf16x8 __attribute__((ext_vector_type(8)));
typedef float f32x4 __attribute__((ext_vector_type(4)));
typedef unsigned int uint32x4 __attribute__((ext_vector_type(4)));
typedef unsigned int uint32x2 __attribute__((ext_vector_type(2)));

__device__ __forceinline__ float atanh_ref(float x) {
  x = fminf(x, 1.0f - EPSF);
  return 0.5f * (log1pf(x + EPSF) - log1pf(EPSF - x));
}

__device__ __forceinline__ unsigned short f2bf(float x) {
  unsigned int u = __float_as_uint(x);
  unsigned int r = (u + 0x7fffu + ((u >> 16) & 1u)) >> 16;
  return (unsigned short)r;
}
__device__ __forceinline__ float bf2f(unsigned short h) {
  return __uint_as_float(((unsigned int)h) << 16);
}

__device__ __forceinline__ void gload16(const void* g, void* l) {
  __builtin_amdgcn_global_load_lds(
      (const __attribute__((address_space(1))) unsigned int*)g,
      (__attribute__((address_space(3))) unsigned int*)l, 16, 0, 0);
}

// ---- explicit MALL-coherent (write-through / read-through) accessors ------
// sc0+sc1 = system scope on gfx940+: bypasses L1 and (non-coherent) L2.
// 16B read-through load; caller MUST s_waitcnt vmcnt(0) before using result.
__device__ __forceinline__ uint32x4 ldg_sc16(const void* p) {
  uint32x4 r;
  asm volatile("global_load_dwordx4 %0, %1, off sc0 sc1" : "=v"(r) : "v"(p));
  return r;
}
// 4B read-through load with fused wait (safe standalone).
__device__ __forceinline__ unsigned ldg_sc4_wait(const void* p) {
  unsigned r;
  asm volatile("global_load_dword %0, %1, off sc0 sc1\n\ts_waitcnt vmcnt(0)"
               : "=v"(r) : "v"(p) : "memory");
  return r;
}
// write-through stores. NOTE: INVISIBLE to the compiler's waitcnt pass —
// any ordering against them must use an explicit asm s_waitcnt vmcnt(0).
__device__ __forceinline__ void stg_sc4(void* p, unsigned v) {
  asm volatile("global_store_dword %0, %1, off sc0 sc1" :: "v"(p), "v"(v) : "memory");
}
__device__ __forceinline__ void stg_sc8(void* p, uint32x2 v) {
  asm volatile("global_store_dwordx2 %0, %1, off sc0 sc1" :: "v"(p), "v"(v) : "memory");
}
// Drain ALL outstanding VMEM of this wave (hardware counter covers inline-asm
// ops the compiler cannot see).
__device__ __forceinline__ void drain_vmem() {
  asm volatile("s_waitcnt vmcnt(0)" ::: "memory");
}
__device__ __forceinline__ bf16x8 as_bf(uint32x4 x) {
  return __builtin_bit_cast(bf16x8, x);
}

// reduce two values across a 256-thread block; result broadcast to all threads
__device__ __forceinline__ void block_reduce2(float& v0, float& v1, float* lds) {
  #pragma unroll
  for (int off = 32; off > 0; off >>= 1) {
    v0 += __shfl_down(v0, off, 64);
    v1 += __shfl_down(v1, off, 64);
  }
  const int lane = threadIdx.x & 63;
  const int wid  = threadIdx.x >> 6;
  if (lane == 0) { lds[wid * 2] = v0; lds[wid * 2 + 1] = v1; }
  __syncthreads();
  if (threadIdx.x == 0) {
    float s0 = 0.f, s1 = 0.f;
    #pragma unroll
    for (int w = 0; w < 4; ++w) { s0 += lds[w * 2]; s1 += lds[w * 2 + 1]; }
    lds[0] = s0; lds[1] = s1;
  }
  __syncthreads();
  v0 = lds[0]; v1 = lds[1];
  __syncthreads();
}

// ---------------------------------------------------------------------------
// Fence-free 64-block barrier (per rg half; halves never exchange data).
// Per-wave drain_vmem() BEFORE __syncthreads() (r7 fix: asm sc-stores are
// invisible to the compiler's waitcnt pass), then flag store, then relaxed
// read-through poll of the 64 flags (1 per lane). No L2 invalidation ever.
// ---------------------------------------------------------------------------
__device__ __forceinline__ void gbar3(unsigned* __restrict__ flags, int rg,
                                      int ci, unsigned target) {
  drain_vmem();     // covers asm sc-stores + atomics of this wave
  __syncthreads();  // all waves of the block have drained
  if (threadIdx.x == 0)
    stg_sc4(flags + rg * 64 + ci, target);
  if (threadIdx.x < 64) {
    const unsigned* p0 = flags + rg * 64 + threadIdx.x;
    for (;;) {
      unsigned f0;
      asm volatile("global_load_dword %0, %1, off sc0 sc1\n\t"
                   "s_waitcnt vmcnt(0)"
                   : "=v"(f0) : "v"(p0) : "memory");
      if (__all(f0 >= target)) break;
      __builtin_amdgcn_s_sleep(2);
    }
  }
  __syncthreads();
}

// ---------------------------------------------------------------------------
// Convert inputs to bf16 hi/lo planes, permuting rows (b*256+t) -> (t*64+b).
// ---------------------------------------------------------------------------
__global__ __launch_bounds__(256) void convert_a(const float* __restrict__ inp,
                                                 unsigned short* __restrict__ Ah,
                                                 unsigned short* __restrict__ Al) {
  const int i = blockIdx.x;
  const int r = ((i & 255) << 6) + (i >> 8);
  const float* src = inp + (size_t)i * KDIM;
  unsigned short* dh = Ah + (size_t)r * KDIM;
  unsigned short* dl = Al + (size_t)r * KDIM;
  const int base = threadIdx.x * 8;
  float4 v0 = *(const float4*)(src + base);
  float4 v1 = *(const float4*)(src + base + 4);
  float f[8] = {v0.x, v0.y, v0.z, v0.w, v1.x, v1.y, v1.z, v1.w};
  unsigned short h[8], l[8];
  #pragma unroll
  for (int j = 0; j < 8; ++j) {
    unsigned short hb = f2bf(f[j]);
    h[j] = hb;
    l[j] = f2bf(f[j] - bf2f(hb));
  }
  *(bf16x8*)(dh + base) = *(bf16x8*)h;
  *(bf16x8*)(dl + base) = *(bf16x8*)l;
}

// ---------------------------------------------------------------------------
// Transpose + convert M (2048x2048) into M^T bf16 hi/lo: Bt[n][k] = M[k][n].
// ---------------------------------------------------------------------------
__global__ __launch_bounds__(256) void convert_bt(const float* __restrict__ M,
                                                  unsigned short* __restrict__ Bh,
                                                  unsigned short* __restrict__ Bl) {
  __shared__ float t[64][65];
  const int k0 = blockIdx.y * 64, nn0 = blockIdx.x * 64;
  const int tid = threadIdx.x;
  #pragma unroll
  for (int j = 0; j < 4; ++j) {
    int idx = tid + j * 256;
    int r = idx >> 4, c4 = (idx & 15) * 4;
    float4 v = *(const float4*)(M + (size_t)(k0 + r) * KDIM + nn0 + c4);
    t[r][c4 + 0] = v.x; t[r][c4 + 1] = v.y; t[r][c4 + 2] = v.z; t[r][c4 + 3] = v.w;
  }
  __syncthreads();
  #pragma unroll
  for (int j = 0; j < 4; ++j) {
    int idx = tid + j * 256;
    int n = idx >> 4, ks = (idx & 15) * 4;
    unsigned short hh[4], ll[4];
    #pragma unroll
    for (int q = 0; q < 4; ++q) {
      float x = t[ks + q][n];
      unsigned short hb = f2bf(x);
      hh[q] = hb;
      ll[q] = f2bf(x - bf2f(hb));
    }
    *(ushort4*)(Bh + (size_t)(nn0 + n) * KDIM + k0 + ks) = *(ushort4*)hh;
    *(ushort4*)(Bl + (size_t)(nn0 + n) * KDIM + k0 + ks) = *(ushort4*)ll;
  }
}

// ---------------------------------------------------------------------------
// bf16x3-split MFMA GEMM for Ux.
// ---------------------------------------------------------------------------
__global__ __launch_bounds__(256) void gemm_mfma3(const unsigned short* __restrict__ Ah,
                                                  const unsigned short* __restrict__ Al,
                                                  const unsigned short* __restrict__ Bh,
                                                  const unsigned short* __restrict__ Bl,
                                                  float* __restrict__ C) {
  __shared__ unsigned char LAh[8192], LAl[8192], LBh[8192], LBl[8192];
  const int tid = threadIdx.x;
  const int lane = tid & 63;
  const int w = tid >> 6;
  const int wr = w >> 1, wc = w & 1;
  const int m0 = blockIdx.x * 128;
  const int n0 = blockIdx.y * 128;

  f32x4 acc[4][4] = {};

  for (int k0 = 0; k0 < KDIM; k0 += 32) {
    #pragma unroll
    for (int j = 0; j < 2; ++j) {
      int c = j * 256 + tid;
      int row = c >> 2;
      int sp = (c & 3) ^ (row & 3);
      size_t aoff = (size_t)(m0 + row) * KDIM + k0 + sp * 8;
      size_t boff = (size_t)(n0 + row) * KDIM + k0 + sp * 8;
      int ldsb = (j * 256 + w * 64) * 16;
      gload16(Ah + aoff, LAh + ldsb);
      gload16(Al + aoff, LAl + ldsb);
      gload16(Bh + boff, LBh + ldsb);
      gload16(Bl + boff, LBl + ldsb);
    }
    __syncthreads();
    bf16x8 ah[4], al[4], bh[4], bl[4];
    #pragma unroll
    for (int i = 0; i < 4; ++i) {
      int arow = wr * 64 + i * 16 + (lane & 15);
      int abyte = arow * 64 + (((lane >> 4) ^ (arow & 3)) * 16);
      ah[i] = *(const bf16x8*)(LAh + abyte);
      al[i] = *(const bf16x8*)(LAl + abyte);
      int brow = wc * 64 + i * 16 + (lane & 15);
      int bbyte = brow * 64 + (((lane >> 4) ^ (brow & 3)) * 16);
      bh[i] = *(const bf16x8*)(LBh + bbyte);
      bl[i] = *(const bf16x8*)(LBl + bbyte);
    }
    #pragma unroll
    for (int i = 0; i < 4; ++i)
      #pragma unroll
      for (int jn = 0; jn < 4; ++jn) {
        acc[i][jn] = __builtin_amdgcn_mfma_f32_16x16x32_bf16(ah[i], bh[jn], acc[i][jn], 0, 0, 0);
        acc[i][jn] = __builtin_amdgcn_mfma_f32_16x16x32_bf16(ah[i], bl[jn], acc[i][jn], 0, 0, 0);
        acc[i][jn] = __builtin_amdgcn_mfma_f32_16x16x32_bf16(al[i], bh[jn], acc[i][jn], 0, 0, 0);
      }
    __syncthreads();
  }
  #pragma unroll
  for (int i = 0; i < 4; ++i) {
    int grow = m0 + wr * 64 + i * 16 + ((lane >> 4) << 2);
    #pragma unroll
    for (int jn = 0; jn < 4; ++jn) {
      int gcol = n0 + wc * 64 + jn * 16 + (lane & 15);
      #pragma unroll
      for (int r = 0; r < 4; ++r)
        C[(size_t)(grow + r) * KDIM + gcol] = acc[i][jn][r];
    }
  }
}

// ---------------------------------------------------------------------------
// Mobius epilogue for the big GEMM (in-place on Mx -> Ux). One block per row.
// ---------------------------------------------------------------------------
__global__ __launch_bounds__(256) void ux_epilogue(const float* __restrict__ inp,
                                                   float* __restrict__ Mx) {
  const int r = blockIdx.x;
  const int t = r >> 6, b = r & 63;
  const float* xrow = inp + ((size_t)(b * T_DIM + t)) * KDIM;
  float* mrow = Mx + (size_t)r * KDIM;
  const int tid = threadIdx.x;
  __shared__ float lds[8];
  float xs2 = 0.f, ms2 = 0.f;
  float m[8];
  #pragma unroll
  for (int j = 0; j < 8; ++j) {
    const int col = tid + j * 256;
    float xv = xrow[col] + EPSF;
    xs2 += xv * xv;
    float mv = mrow[col];
    m[j] = mv;
    ms2 += mv * mv;
  }
  block_reduce2(xs2, ms2, lds);
  float xn = sqrtf(xs2);
  float mnr = sqrtf(ms2);
  float mxn = mnr + EPSF;
  float s = tanhf((mxn / xn) * atanh_ref(xn)) / mxn;
  float na = s * mnr;
  float pf = fminf(1.0f, MAXN / fmaxf(na, EPSF));
  float sc = s * pf;
  #pragma unroll
  for (int j = 0; j < 8; ++j)
    mrow[tid + j * 256] = m[j] * sc;
}

// ---------------------------------------------------------------------------
// Init for the persistent scan: h = 0+EPS (bf16 hi/lo), pd accumulators
// (zeroed; parity-0 hn2 = 2048*EPS^2), bvbv scalar, flag vector.
// pd layout: pd[par 0..1][val 0..5][row 0..63]  (val 5 = hn2)
// ---------------------------------------------------------------------------
__global__ __launch_bounds__(256) void scan_init(unsigned short* __restrict__ hh_,
                                                 unsigned short* __restrict__ hl_,
                                                 float* __restrict__ pd,
                                                 const float* __restrict__ bvec,
                                                 float* __restrict__ bvbvp,
                                                 unsigned* __restrict__ flags) {
  const int bx = blockIdx.x;  // 64 blocks
  const int tid = threadIdx.x;
  const unsigned short he = f2bf(EPSF);
  const unsigned short le = f2bf(EPSF - bf2f(he));
  #pragma unroll
  for (int j = 0; j < 8; ++j) {
    int c = tid + j * 256;
    hh_[(size_t)bx * KDIM + c] = he;
    hl_[(size_t)bx * KDIM + c] = le;
  }
  if (bx == 0) {
    for (int i = tid; i < 768; i += 256) {
      bool hn2slot = (i >= 320) && (i < 384);  // par0, val5
      float v = hn2slot ? (2048.0f * EPSF * EPSF) : 0.0f;
      stg_sc4(pd + i, __float_as_uint(v));
    }
    if (tid < NBLK) stg_sc4(flags + tid, 0u);
    drain_vmem();              // asm stores are untracked; drain before endpgm
  }
  if (bx == 1) {
    __shared__ float lds[8];
    float s = 0.f;
    #pragma unroll
    for (int j = 0; j < 8; ++j) {
      float v = bvec[tid + j * 256] + EPSF;
      s += v * v;
    }
    float dummy = 0.f;
    block_reduce2(s, dummy, lds);
    if (tid == 0) *bvbvp = s;
  }
}

// ---------------------------------------------------------------------------
// Persistent whole-scan kernel. 128 blocks x 256 threads, fence-free.
// Block = rg half (32 batch rows) x 32-col slice; XCD-grouped so each XCD's
// 2.1 MB W^T panel stays L2-resident. h-broadcast halved vs the 256-block
// config (32 MB/step of sc read-through traffic). Protocol identical to r7:
// drain -> flag -> poll -> read-through; pd via relaxed agent atomicAdd.
// ---------------------------------------------------------------------------
__global__ __launch_bounds__(256) void scan_coop(const unsigned short* __restrict__ Wth,
                                                 const unsigned short* __restrict__ Wtl,
                                                 unsigned short* __restrict__ hh_,
                                                 unsigned short* __restrict__ hl_,
                                                 const float* __restrict__ Ux,
                                                 const float* __restrict__ bvec,
                                                 float* __restrict__ pd,
                                                 const float* __restrict__ bvbvp,
                                                 unsigned* __restrict__ flags,
                                                 float* __restrict__ out) {
  const int tid = threadIdx.x;
  const int bx = blockIdx.x;
  const int lane = tid & 63;
  const int w = tid >> 6;
  // bits[2:0]=xcd, bit3=rg, bits[6:4]=s  -> cs = xcd*8 + s (XCD-grouped)
  const int rg = (bx >> 3) & 1;
  const int cs = (bx & 7) * 8 + (bx >> 4);      // 0..63
  const int ci = cs;                            // barrier slot within rg-half
  const int gc0 = cs * 32;
  const int r = tid >> 3;                       // row within 32
  const int b = rg * 32 + r;                    // batch row
  const int gc = gc0 + (tid & 7) * 4;           // 4 cols per thread

  __shared__ float wtmp[4][32][32];
  __shared__ float MhL[32][32];
  __shared__ float red[32][6];
  __shared__ float cf[32][3];

  const float bvbv = *bvbvp;
  float bv[4];
  {
    float4 b4 = *(const float4*)(bvec + gc);
    bv[0] = b4.x + EPSF; bv[1] = b4.y + EPSF;
    bv[2] = b4.z + EPSF; bv[3] = b4.w + EPSF;
  }

  const int arow0 = (rg * 32 + (lane & 15)) * KDIM;
  const int arow1 = (rg * 32 + 16 + (lane & 15)) * KDIM;
  const int brow0 = (gc0 + (lane & 15)) * KDIM;
  const int brow1 = (gc0 + 16 + (lane & 15)) * KDIM;
  const int ksub = w * 512 + (lane >> 4) * 8;

  for (int t = 0; t < T_DIM; ++t) {
    const int par = t & 1;
    // zero the OTHER parity's accumulators (write-through; barrier-separated
    // from all readers).
    if (tid < 192) {
      int v = tid >> 5, rr = tid & 31;
      stg_sc4(pd + (((size_t)(par ^ 1) * 6 + v) * 64 + rg * 32 + rr), 0u);
    }

    // ---- phase A: Mh tile (32x32) via bf16x3 MFMA, wave-split-K ----
    f32x4 acc[2][2] = {};
    #pragma unroll
    for (int g = 0; g < 4; ++g) {
      uint32x4 xb[16];
      bf16x8 wb[16];
      #pragma unroll
      for (int q = 0; q < 4; ++q) {
        const int kq = ksub + (g * 4 + q) * 32;
        xb[q * 4 + 0] = ldg_sc16(hh_ + arow0 + kq);
        xb[q * 4 + 1] = ldg_sc16(hl_ + arow0 + kq);
        xb[q * 4 + 2] = ldg_sc16(hh_ + arow1 + kq);
        xb[q * 4 + 3] = ldg_sc16(hl_ + arow1 + kq);
        wb[q * 4 + 0] = *(const bf16x8*)(Wth + brow0 + kq);
        wb[q * 4 + 1] = *(const bf16x8*)(Wtl + brow0 + kq);
        wb[q * 4 + 2] = *(const bf16x8*)(Wth + brow1 + kq);
        wb[q * 4 + 3] = *(const bf16x8*)(Wtl + brow1 + kq);
      }
      asm volatile("s_waitcnt vmcnt(0)" ::: "memory");
      __builtin_amdgcn_sched_barrier(0);
      #pragma unroll
      for (int q = 0; q < 4; ++q) {
        bf16x8 a0h = as_bf(xb[q * 4 + 0]);
        bf16x8 a0l = as_bf(xb[q * 4 + 1]);
        bf16x8 a1h = as_bf(xb[q * 4 + 2]);
        bf16x8 a1l = as_bf(xb[q * 4 + 3]);
        bf16x8 b0h = wb[q * 4 + 0];
        bf16x8 b0l = wb[q * 4 + 1];
        bf16x8 b1h = wb[q * 4 + 2];
        bf16x8 b1l = wb[q * 4 + 3];
        acc[0][0] = __builtin_amdgcn_mfma_f32_16x16x32_bf16(a0h, b0h, acc[0][0], 0, 0, 0);
        acc[0][0] = __builtin_amdgcn_mfma_f32_16x16x32_bf16(a0h, b0l, acc[0][0], 0, 0, 0);
        acc[0][0] = __builtin_amdgcn_mfma_f32_16x16x32_bf16(a0l, b0h, acc[0][0], 0, 0, 0);
        acc[0][1] = __builtin_amdgcn_mfma_f32_16x16x32_bf16(a0h, b1h, acc[0][1], 0, 0, 0);
        acc[0][1] = __builtin_amdgcn_mfma_f32_16x16x32_bf16(a0h, b1l, acc[0][1], 0, 0, 0);
        acc[0][1] = __builtin_amdgcn_mfma_f32_16x16x32_bf16(a0l, b1h, acc[0][1], 0, 0, 0);
        acc[1][0] = __builtin_amdgcn_mfma_f32_16x16x32_bf16(a1h, b0h, acc[1][0], 0, 0, 0);
        acc[1][0] = __builtin_amdgcn_mfma_f32_16x16x32_bf16(a1h, b0l, acc[1][0], 0, 0, 0);
        acc[1][0] = __builtin_amdgcn_mfma_f32_16x16x32_bf16(a1l, b0h, acc[1][0], 0, 0, 0);
        acc[1][1] = __builtin_amdgcn_mfma_f32_16x16x32_bf16(a1h, b1h, acc[1][1], 0, 0, 0);
        acc[1][1] = __builtin_amdgcn_mfma_f32_16x16x32_bf16(a1h, b1l, acc[1][1], 0, 0, 0);
        acc[1][1] = __builtin_amdgcn_mfma_f32_16x16x32_bf16(a1l, b1h, acc[1][1], 0, 0, 0);
      }
    }
    #pragma unroll
    for (int q = 0; q < 4; ++q) {
      const int rr = (lane >> 4) * 4 + q;
      const int cc = lane & 15;
      wtmp[w][rr][cc]           = acc[0][0][q];
      wtmp[w][rr][16 + cc]      = acc[0][1][q];
      wtmp[w][16 + rr][cc]      = acc[1][0][q];
      wtmp[w][16 + rr][16 + cc] = acc[1][1][q];
    }
    __syncthreads();
    #pragma unroll
    for (int k = 0; k < 4; ++k) {
      int e = tid + k * 256;
      int rr = e >> 5, cc = e & 31;
      MhL[rr][cc] = wtmp[0][rr][cc] + wtmp[1][rr][cc] + wtmp[2][rr][cc] + wtmp[3][rr][cc];
    }
    __syncthreads();
    float mh[4], ux[4];
    #pragma unroll
    for (int j = 0; j < 4; ++j) mh[j] = MhL[r][(tid & 7) * 4 + j];
    {
      f32x4 u4 = __builtin_nontemporal_load(
          reinterpret_cast<const f32x4*>(Ux + ((size_t)t * 64 + b) * KDIM + gc));
      ux[0] = u4[0] + EPSF; ux[1] = u4[1] + EPSF;
      ux[2] = u4[2] + EPSF; ux[3] = u4[3] + EPSF;
    }
    float dt0 = 0.f, dt1 = 0.f, dt2 = 0.f, dt3 = 0.f, dt4 = 0.f;
    #pragma unroll
    for (int j = 0; j < 4; ++j) {
      dt0 += mh[j] * mh[j];
      dt1 += mh[j] * ux[j];
      dt2 += ux[j] * ux[j];
      dt3 += mh[j] * bv[j];
      dt4 += ux[j] * bv[j];
    }
    #pragma unroll
    for (int off = 4; off > 0; off >>= 1) {
      dt0 += __shfl_down(dt0, off, 8);
      dt1 += __shfl_down(dt1, off, 8);
      dt2 += __shfl_down(dt2, off, 8);
      dt3 += __shfl_down(dt3, off, 8);
      dt4 += __shfl_down(dt4, off, 8);
    }
    if ((tid & 7) == 0) {
      float dts[5] = {dt0, dt1, dt2, dt3, dt4};
      #pragma unroll
      for (int v = 0; v < 5; ++v)
        __hip_atomic_fetch_add(pd + (((size_t)par * 6 + v) * 64 + b), dts[v],
                               __ATOMIC_RELAXED, __HIP_MEMORY_SCOPE_AGENT);
    }
    gbar3(flags, rg, ci, (unsigned)(2 * t + 1));

    // ---- phase B: read accumulated dots (read-through), scalar chain ----
    if (tid < 192) {
      int v = tid >> 5, rr = tid & 31;
      unsigned u = ldg_sc4_wait(pd + (((size_t)par * 6 + v) * 64 + rg * 32 + rr));
      red[rr][v] = __uint_as_float(u);
    }
    __syncthreads();
    if (tid < 32) {
      const float mn2 = red[tid][0], Mhux = red[tid][1], uxux = red[tid][2];
      const float Mhbv = red[tid][3], uxbv = red[tid][4], hn2 = red[tid][5];
      const float hn = sqrtf(hn2);
      const float mnr = sqrtf(mn2);
      const float mxn = mnr + EPSF;
      const float s = tanhf((mxn / hn) * atanh_ref(hn)) / mxn;
      const float n_a = s * mnr;
      const float pfa = fminf(1.0f, MAXN / fmaxf(n_a, EPSF));
      const float sa = s * pfa;
      const float duv = 2.0f * sa * Mhux;
      const float nv = uxux;
      const float na = sa * sa * mn2;
      const float denom = 1.0f + duv + na * nv;
      const float c1 = (1.0f + duv + nv) / denom;
      const float c2 = (1.0f - na) / denom;
      const float r1n2 = c1 * c1 * na + 2.0f * c1 * c2 * sa * Mhux + c2 * c2 * uxux;
      const float pf1 = fminf(1.0f, MAXN / fmaxf(sqrtf(r1n2), EPSF));
      const float Sr1bv = c1 * sa * Mhbv + c2 * uxbv;
      const float duv2 = 2.0f * pf1 * Sr1bv;
      const float na2 = pf1 * pf1 * r1n2;
      const float denom2 = 1.0f + duv2 + na2 * bvbv;
      const float d1 = (1.0f + duv2 + bvbv) / denom2;
      const float d2 = (1.0f - na2) / denom2;
      const float r2n2 = d1 * d1 * na2 + 2.0f * d1 * d2 * pf1 * Sr1bv + d2 * d2 * bvbv;
      const float pf2 = fminf(1.0f, MAXN / fmaxf(sqrtf(r2n2), EPSF));
      cf[tid][0] = pf2 * d1 * pf1 * c1 * sa;  // K_mh
      cf[tid][1] = pf2 * d1 * pf1 * c2;       // K_ux
      cf[tid][2] = pf2 * d2;                  // K_bv
    }
    __syncthreads();
    const float Km = cf[r][0], Ku = cf[r][1], Kb = cf[r][2];
    float hv[4];
    #pragma unroll
    for (int j = 0; j < 4; ++j) hv[j] = Km * mh[j] + Ku * ux[j] + Kb * bv[j];
    {
      f32x4 o4;
      o4[0] = hv[0]; o4[1] = hv[1]; o4[2] = hv[2]; o4[3] = hv[3];
      __builtin_nontemporal_store(
          o4, reinterpret_cast<f32x4*>(out + ((size_t)b * T_DIM + t) * KDIM + gc));
    }
    unsigned short eb[4], lb[4];
    float hn2p = 0.f;
    #pragma unroll
    for (int j = 0; j < 4; ++j) {
      float hp = hv[j] + EPSF;
      eb[j] = f2bf(hp);
      lb[j] = f2bf(hp - bf2f(eb[j]));
      hn2p += hp * hp;
    }
    uint32x2 hhu, hlu;
    hhu[0] = (unsigned)eb[0] | ((unsigned)eb[1] << 16);
    hhu[1] = (unsigned)eb[2] | ((unsigned)eb[3] << 16);
    hlu[0] = (unsigned)lb[0] | ((unsigned)lb[1] << 16);
    hlu[1] = (unsigned)lb[2] | ((unsigned)lb[3] << 16);
    stg_sc8(hh_ + (size_t)b * KDIM + gc, hhu);   // write-through to MALL
    stg_sc8(hl_ + (size_t)b * KDIM + gc, hlu);
    #pragma unroll
    for (int off = 4; off > 0; off >>= 1) hn2p += __shfl_down(hn2p, off, 8);
    if ((tid & 7) == 0)
      __hip_atomic_fetch_add(pd + (((size_t)(par ^ 1) * 6 + 5) * 64 + b), hn2p,
                             __ATOMIC_RELAXED, __HIP_MEMORY_SCOPE_AGENT);
    gbar3(flags, rg, ci, (unsigned)(2 * t + 2));
  }
}

// ---------------------------------------------------------------------------
// Fallback kernels (small-workspace paths).
// ---------------------------------------------------------------------------
__global__ __launch_bounds__(256) void gemm64_splitk(const float* __restrict__ A,
                                                     size_t arstride,
                                                     const float* __restrict__ Bm,
                                                     float* __restrict__ part) {
  const int n0 = blockIdx.x * 64;
  const int kz = blockIdx.y;
  const int kbeg = kz * 256;
  __shared__ float As[16][68];
  __shared__ float Bs[16][64];
  const int tid = threadIdx.x;
  const int tx = tid & 15, ty = tid >> 4;
  const int ai = tid >> 2, ak = (tid & 3) * 4;
  const int bk = tid >> 4, bn = (tid & 15) * 4;
  const float* Arow = A + (size_t)ai * arstride;
  float acc[4][4] = {};
  for (int kt = 0; kt < 16; ++kt) {
    const int k0 = kbeg + kt * 16;
    float4 av = *(const float4*)(Arow + k0 + ak);
    As[ak + 0][ai] = av.x + EPSF;
    As[ak + 1][ai] = av.y + EPSF;
    As[ak + 2][ai] = av.z + EPSF;
    As[ak + 3][ai] = av.w + EPSF;
    float4 bv = *(const float4*)(Bm + (size_t)(k0 + bk) * KDIM + n0 + bn);
    *(float4*)&Bs[bk][bn] = bv;
    __syncthreads();
    #pragma unroll
    for (int k = 0; k < 16; ++k) {
      float4 a4 = *(const float4*)&As[k][ty * 4];
      float4 b4 = *(const float4*)&Bs[k][tx * 4];
      float a[4] = {a4.x, a4.y, a4.z, a4.w};
      float bb[4] = {b4.x, b4.y, b4.z, b4.w};
      #pragma unroll
      for (int i = 0; i < 4; ++i)
        #pragma unroll
        for (int j = 0; j < 4; ++j)
          acc[i][j] = fmaf(a[i], bb[j], acc[i][j]);
    }
    __syncthreads();
  }
  #pragma unroll
  for (int i = 0; i < 4; ++i) {
    float4 o = make_float4(acc[i][0], acc[i][1], acc[i][2], acc[i][3]);
    *(float4*)(part + ((size_t)kz * 64 + ty * 4 + i) * KDIM + n0 + tx * 4) = o;
  }
}

__global__ __launch_bounds__(256) void mob_from_parts(const float* __restrict__ part,
                                                      const float* __restrict__ xbase,
                                                      size_t xstride,
                                                      float* __restrict__ outrows) {
  const int b = blockIdx.x;
  const int tid = threadIdx.x;
  __shared__ float lds[8];
  const float* xrow = xbase + (size_t)b * xstride;
  float xs2 = 0.f, ms2 = 0.f;
  float m[8];
  #pragma unroll
  for (int j = 0; j < 8; ++j) {
    const int col = tid + j * 256;
    float xv = xrow[col] + EPSF;
    xs2 += xv * xv;
    float mv = 0.f;
    for (int kz = 0; kz < 8; ++kz)
      mv += part[((size_t)kz * 64 + b) * KDIM + col];
    m[j] = mv;
    ms2 += mv * mv;
  }
  block_reduce2(xs2, ms2, lds);
  float xn = sqrtf(xs2);
  float mnr = sqrtf(ms2);
  float mxn = mnr + EPSF;
  float s = tanhf((mxn / xn) * atanh_ref(xn)) / mxn;
  float na = s * mnr;
  float pf = fminf(1.0f, MAXN / fmaxf(na, EPSF));
  float sc = s * pf;
  #pragma unroll
  for (int j = 0; j < 8; ++j)
    outrows[(size_t)b * KDIM + tid + j * 256] = m[j] * sc;
}

__global__ __launch_bounds__(256) void step_mobius(const float* __restrict__ part,
                                                   float* __restrict__ h,
                                                   const float* __restrict__ uxrows,
                                                   const float* __restrict__ bvec,
                                                   float* __restrict__ out,
                                                   int t) {
  const int b = blockIdx.x;
  const int tid = threadIdx.x;
  __shared__ float lds[8];
  float mh[8], uxv[8], bv[8];
  float hn2 = 0.f, mn2 = 0.f;
  #pragma unroll
  for (int j = 0; j < 8; ++j) {
    const int col = tid + j * 256;
    float x = h[(size_t)b * KDIM + col] + EPSF;
    hn2 += x * x;
    float m = 0.f;
    for (int kz = 0; kz < 8; ++kz)
      m += part[((size_t)kz * 64 + b) * KDIM + col];
    mh[j] = m;
    mn2 += m * m;
    uxv[j] = uxrows[(size_t)b * KDIM + col] + EPSF;
    bv[j] = bvec[col] + EPSF;
  }
  block_reduce2(hn2, mn2, lds);
  float hn = sqrtf(hn2);
  float mnr = sqrtf(mn2);
  float mxn = mnr + EPSF;
  float s = tanhf((mxn / hn) * atanh_ref(hn)) / mxn;
  float n_a = s * mnr;
  float pfa = fminf(1.0f, MAXN / fmaxf(n_a, EPSF));
  float sa = s * pfa;
  float a[8];
  float duv = 0.f, nv = 0.f;
  #pragma unroll
  for (int j = 0; j < 8; ++j) {
    a[j] = sa * mh[j];
    duv += a[j] * uxv[j];
    nv += uxv[j] * uxv[j];
  }
  block_reduce2(duv, nv, lds);
  duv *= 2.0f;
  float na = sa * sa * mn2;
  float denom = 1.0f + duv + na * nv;
  float c1 = (1.0f + duv + nv) / denom;
  float c2 = (1.0f - na) / denom;
  float r1[8];
  float r1n2 = 0.f, dummy = 0.f;
  #pragma unroll
  for (int j = 0; j < 8; ++j) {
    r1[j] = c1 * a[j] + c2 * uxv[j];
    r1n2 += r1[j] * r1[j];
  }
  block_reduce2(r1n2, dummy, lds);
  float n1 = sqrtf(r1n2);
  float pf1 = fminf(1.0f, MAXN / fmaxf(n1, EPSF));
  float duv2 = 0.f, nv2 = 0.f;
  #pragma unroll
  for (int j = 0; j < 8; ++j) {
    r1[j] *= pf1;
    duv2 += r1[j] * bv[j];
    nv2 += bv[j] * bv[j];
  }
  block_reduce2(duv2, nv2, lds);
  duv2 *= 2.0f;
  float na2 = pf1 * pf1 * r1n2;
  float denom2 = 1.0f + duv2 + na2 * nv2;
  float d1 = (1.0f + duv2 + nv2) / denom2;
  float d2 = (1.0f - na2) / denom2;
  float r2[8];
  float r2n2 = 0.f;
  dummy = 0.f;
  #pragma unroll
  for (int j = 0; j < 8; ++j) {
    r2[j] = d1 * r1[j] + d2 * bv[j];
    r2n2 += r2[j] * r2[j];
  }
  block_reduce2(r2n2, dummy, lds);
  float n2 = sqrtf(r2n2);
  float pf2 = fminf(1.0f, MAXN / fmaxf(n2, EPSF));
  #pragma unroll
  for (int j = 0; j < 8; ++j) {
    const int col = tid + j * 256;
    float vout = r2[j] * pf2;
    h[(size_t)b * KDIM + col] = vout;
    out[((size_t)b * T_DIM + t) * KDIM + col] = vout;
  }
}

extern "C" void kernel_launch(void* const* d_in, const int* in_sizes, int n_in,
                              void* d_out, int out_size, void* d_ws, size_t ws_size,
                              hipStream_t stream) {
  const float* inp  = (const float*)d_in[0];
  const float* wm   = (const float*)d_in[1];
  const float* um   = (const float*)d_in[2];
  const float* bvec = (const float*)d_in[3];
  float* out = (float*)d_out;
  char* ws = (char*)d_ws;

  const size_t UXB  = (size_t)TBROWS * KDIM * 4;   // 134.2 MB
  const size_t AHL  = (size_t)TBROWS * KDIM * 2;   // 67.1 MB
  const size_t BTB  = (size_t)KDIM * KDIM * 2;     // 8.4 MB
  const size_t HB16 = (size_t)B_DIM * KDIM * 2;    // 256 KB
  const size_t PDB  = 4096;                        // 2*6*64 floats (+pad)
  const size_t META = 2048;                        // bvbv + flags
  const size_t HFP  = (size_t)B_DIM * KDIM * 4;    // 512 KB
  const size_t PART = (size_t)8 * B_DIM * KDIM * 4; // 4 MB

  size_t off = 0;
  float* Ux = (float*)(ws + off); off += UXB;
  unsigned short* Ah = (unsigned short*)(ws + off); off += AHL;
  unsigned short* Al = (unsigned short*)(ws + off); off += AHL;
  unsigned short* Bh = (unsigned short*)(ws + off); off += BTB;
  unsigned short* Bl = (unsigned short*)(ws + off); off += BTB;
  unsigned short* Wth = (unsigned short*)(ws + off); off += BTB;
  unsigned short* Wtl = (unsigned short*)(ws + off); off += BTB;
  unsigned short* hh = (unsigned short*)(ws + off); off += HB16;
  unsigned short* hl = (unsigned short*)(ws + off); off += HB16;
  float* pd = (float*)(ws + off); off += PDB;
  float* bvbvp = (float*)(ws + off);
  unsigned* flagsp = (unsigned*)(ws + off + 128); off += META;
  float* hfp = (float*)(ws + off); off += HFP;
  float* part = (float*)(ws + off); off += PART;
  const size_t NEED_COOP = off;
  const size_t NEED_MFMA = UXB + 2 * AHL + 2 * BTB + HFP + PART;
  const size_t NEED_FP32 = UXB + HFP + PART;

  if (ws_size >= NEED_COOP) {
    convert_a<<<TBROWS, 256, 0, stream>>>(inp, Ah, Al);
    convert_bt<<<dim3(32, 32), 256, 0, stream>>>(um, Bh, Bl);
    convert_bt<<<dim3(32, 32), 256, 0, stream>>>(wm, Wth, Wtl);
    scan_init<<<B_DIM, 256, 0, stream>>>(hh, hl, pd, bvec, bvbvp, flagsp);
    gemm_mfma3<<<dim3(128, 16), 256, 0, stream>>>(Ah, Al, Bh, Bl, Ux);
    ux_epilogue<<<TBROWS, 256, 0, stream>>>(inp, Ux);
    scan_coop<<<NBLK, 256, 0, stream>>>(Wth, Wtl, hh, hl, Ux, bvec, pd, bvbvp,
                                        flagsp, out);
  } else if (ws_size >= NEED_MFMA) {
    float* Ux2 = (float*)ws;
    unsigned short* Ah2 = (unsigned short*)(ws + UXB);
    unsigned short* Al2 = (unsigned short*)(ws + UXB + AHL);
    unsigned short* Bh2 = (unsigned short*)(ws + UXB + 2 * AHL);
    unsigned short* Bl2 = (unsigned short*)(ws + UXB + 2 * AHL + BTB);
    float* h2 = (float*)(ws + UXB + 2 * AHL + 2 * BTB);
    float* part2 = (float*)(ws + UXB + 2 * AHL + 2 * BTB + HFP);
    hipMemsetAsync(h2, 0, HFP, stream);
    convert_a<<<TBROWS, 256, 0, stream>>>(inp, Ah2, Al2);
    convert_bt<<<dim3(32, 32), 256, 0, stream>>>(um, Bh2, Bl2);
    gemm_mfma3<<<dim3(128, 16), 256, 0, stream>>>(Ah2, Al2, Bh2, Bl2, Ux2);
    ux_epilogue<<<TBROWS, 256, 0, stream>>>(inp, Ux2);
    for (int t = 0; t < T_DIM; ++t) {
      gemm64_splitk<<<dim3(32, 8), 256, 0, stream>>>(h2, (size_t)KDIM, wm, part2);
      step_mobius<<<B_DIM, 256, 0, stream>>>(part2, h2, Ux2 + (size_t)t * B_DIM * KDIM,
                                             bvec, out, t);
    }
  } else {
    float* h2 = (float*)ws;
    float* part2 = (float*)(ws + HFP);
    float* partU = (float*)(ws + HFP + PART);
    float* uxstep = (float*)(ws + HFP + 2 * PART);
    hipMemsetAsync(h2, 0, HFP, stream);
    for (int t = 0; t < T_DIM; ++t) {
      const float* xt = inp + (size_t)t * KDIM;
      gemm64_splitk<<<dim3(32, 8), 256, 0, stream>>>(xt, (size_t)T_DIM * KDIM, um, partU);
      mob_from_parts<<<B_DIM, 256, 0, stream>>>(partU, xt, (size_t)T_DIM * KDIM, uxstep);
      gemm64_splitk<<<dim3(32, 8), 256, 0, stream>>>(h2, (size_t)KDIM, wm, part2);
      step_mobius<<<B_DIM, 256, 0, stream>>>(part2, h2, uxstep, bvec, out, t);
    }
  }
}

// Round 10
// 6381.928 us; speedup vs baseline: 4.1522x; 1.0278x over previous
//
#include <hip/hip_runtime.h>
#include <math.h>

#define T_DIM 256
#define B_DIM 64
#define KDIM 2048   // I*D == H*D
#define TBROWS 16384
#define NBLK 128    // persistent scan grid: 2 rg x 64 col-slices
#define HSLOT 262144  // ushorts per hx slot: 2 planes x 64 x 2048
#define PDSLOT 384    // floats per pd slot: 6 x 64

constexpr float EPSF = 1e-15f;
constexpr float MAXN = 1.0f - 1e-5f;

typedef short bf16x8 __attribute__((ext_vector_type(8)));
typedef float f32x4 __attribute__((ext_vector_type(4)));
typedef unsigned int uint32x4 __attribute__((ext_vector_type(4)));
typedef unsigned int uint32x2 __attribute__((ext_vector_type(2)));

__device__ __forceinline__ float atanh_ref(float x) {
  x = fminf(x, 1.0f - EPSF);
  return 0.5f * (log1pf(x + EPSF) - log1pf(EPSF - x));
}

__device__ __forceinline__ unsigned short f2bf(float x) {
  unsigned int u = __float_as_uint(x);
  unsigned int r = (u + 0x7fffu + ((u >> 16) & 1u)) >> 16;
  return (unsigned short)r;
}
__device__ __forceinline__ float bf2f(unsigned short h) {
  return __uint_as_float(((unsigned int)h) << 16);
}

__device__ __forceinline__ void gload16(const void* g, void* l) {
  __builtin_amdgcn_global_load_lds(
      (const __attribute__((address_space(1))) unsigned int*)g,
      (__attribute__((address_space(3))) unsigned int*)l, 16, 0, 0);
}

// ---- explicit MALL write-through / read-through accessors (sc0+sc1) ------
__device__ __forceinline__ void stg_sc4(void* p, unsigned v) {
  asm volatile("global_store_dword %0, %1, off sc0 sc1" :: "v"(p), "v"(v) : "memory");
}
__device__ __forceinline__ void stg_sc8(void* p, uint32x2 v) {
  asm volatile("global_store_dwordx2 %0, %1, off sc0 sc1" :: "v"(p), "v"(v) : "memory");
}
// Drain ALL outstanding VMEM of this wave (hardware counter covers inline-asm
// ops the compiler cannot see).
__device__ __forceinline__ void drain_vmem() {
  asm volatile("s_waitcnt vmcnt(0)" ::: "memory");
}

// reduce two values across a 256-thread block; result broadcast to all threads
__device__ __forceinline__ void block_reduce2(float& v0, float& v1, float* lds) {
  #pragma unroll
  for (int off = 32; off > 0; off >>= 1) {
    v0 += __shfl_down(v0, off, 64);
    v1 += __shfl_down(v1, off, 64);
  }
  const int lane = threadIdx.x & 63;
  const int wid  = threadIdx.x >> 6;
  if (lane == 0) { lds[wid * 2] = v0; lds[wid * 2 + 1] = v1; }
  __syncthreads();
  if (threadIdx.x == 0) {
    float s0 = 0.f, s1 = 0.f;
    #pragma unroll
    for (int w = 0; w < 4; ++w) { s0 += lds[w * 2]; s1 += lds[w * 2 + 1]; }
    lds[0] = s0; lds[1] = s1;
  }
  __syncthreads();
  v0 = lds[0]; v1 = lds[1];
  __syncthreads();
}

// ---------------------------------------------------------------------------
// Fence-free 64-block barrier (per rg half). drain_vmem() BEFORE syncthreads
// (asm sc-stores invisible to compiler waitcnt pass), flag sc-store, sc-poll.
// ---------------------------------------------------------------------------
__device__ __forceinline__ void gbar3(unsigned* __restrict__ flags, int rg,
                                      int ci, unsigned target) {
  drain_vmem();
  __syncthreads();
  if (threadIdx.x == 0)
    stg_sc4(flags + rg * 64 + ci, target);
  if (threadIdx.x < 64) {
    const unsigned* p0 = flags + rg * 64 + threadIdx.x;
    for (;;) {
      unsigned f0;
      asm volatile("global_load_dword %0, %1, off sc0 sc1\n\t"
                   "s_waitcnt vmcnt(0)"
                   : "=v"(f0) : "v"(p0) : "memory");
      if (__all(f0 >= target)) break;
      __builtin_amdgcn_s_sleep(2);
    }
  }
  __syncthreads();
}

// ---------------------------------------------------------------------------
// Convert inputs to bf16 hi/lo planes, permuting rows (b*256+t) -> (t*64+b).
// ---------------------------------------------------------------------------
__global__ __launch_bounds__(256) void convert_a(const float* __restrict__ inp,
                                                 unsigned short* __restrict__ Ah,
                                                 unsigned short* __restrict__ Al) {
  const int i = blockIdx.x;
  const int r = ((i & 255) << 6) + (i >> 8);
  const float* src = inp + (size_t)i * KDIM;
  unsigned short* dh = Ah + (size_t)r * KDIM;
  unsigned short* dl = Al + (size_t)r * KDIM;
  const int base = threadIdx.x * 8;
  float4 v0 = *(const float4*)(src + base);
  float4 v1 = *(const float4*)(src + base + 4);
  float f[8] = {v0.x, v0.y, v0.z, v0.w, v1.x, v1.y, v1.z, v1.w};
  unsigned short h[8], l[8];
  #pragma unroll
  for (int j = 0; j < 8; ++j) {
    unsigned short hb = f2bf(f[j]);
    h[j] = hb;
    l[j] = f2bf(f[j] - bf2f(hb));
  }
  *(bf16x8*)(dh + base) = *(bf16x8*)h;
  *(bf16x8*)(dl + base) = *(bf16x8*)l;
}

// ---------------------------------------------------------------------------
// Transpose + convert M (2048x2048) into M^T bf16 hi/lo: Bt[n][k] = M[k][n].
// ---------------------------------------------------------------------------
__global__ __launch_bounds__(256) void convert_bt(const float* __restrict__ M,
                                                  unsigned short* __restrict__ Bh,
                                                  unsigned short* __restrict__ Bl) {
  __shared__ float t[64][65];
  const int k0 = blockIdx.y * 64, nn0 = blockIdx.x * 64;
  const int tid = threadIdx.x;
  #pragma unroll
  for (int j = 0; j < 4; ++j) {
    int idx = tid + j * 256;
    int r = idx >> 4, c4 = (idx & 15) * 4;
    float4 v = *(const float4*)(M + (size_t)(k0 + r) * KDIM + nn0 + c4);
    t[r][c4 + 0] = v.x; t[r][c4 + 1] = v.y; t[r][c4 + 2] = v.z; t[r][c4 + 3] = v.w;
  }
  __syncthreads();
  #pragma unroll
  for (int j = 0; j < 4; ++j) {
    int idx = tid + j * 256;
    int n = idx >> 4, ks = (idx & 15) * 4;
    unsigned short hh[4], ll[4];
    #pragma unroll
    for (int q = 0; q < 4; ++q) {
      float x = t[ks + q][n];
      unsigned short hb = f2bf(x);
      hh[q] = hb;
      ll[q] = f2bf(x - bf2f(hb));
    }
    *(ushort4*)(Bh + (size_t)(nn0 + n) * KDIM + k0 + ks) = *(ushort4*)hh;
    *(ushort4*)(Bl + (size_t)(nn0 + n) * KDIM + k0 + ks) = *(ushort4*)ll;
  }
}

// ---------------------------------------------------------------------------
// bf16x3-split MFMA GEMM for Ux.
// ---------------------------------------------------------------------------
__global__ __launch_bounds__(256) void gemm_mfma3(const unsigned short* __restrict__ Ah,
                                                  const unsigned short* __restrict__ Al,
                                                  const unsigned short* __restrict__ Bh,
                                                  const unsigned short* __restrict__ Bl,
                                                  float* __restrict__ C) {
  __shared__ unsigned char LAh[8192], LAl[8192], LBh[8192], LBl[8192];
  const int tid = threadIdx.x;
  const int lane = tid & 63;
  const int w = tid >> 6;
  const int wr = w >> 1, wc = w & 1;
  const int m0 = blockIdx.x * 128;
  const int n0 = blockIdx.y * 128;

  f32x4 acc[4][4] = {};

  for (int k0 = 0; k0 < KDIM; k0 += 32) {
    #pragma unroll
    for (int j = 0; j < 2; ++j) {
      int c = j * 256 + tid;
      int row = c >> 2;
      int sp = (c & 3) ^ (row & 3);
      size_t aoff = (size_t)(m0 + row) * KDIM + k0 + sp * 8;
      size_t boff = (size_t)(n0 + row) * KDIM + k0 + sp * 8;
      int ldsb = (j * 256 + w * 64) * 16;
      gload16(Ah + aoff, LAh + ldsb);
      gload16(Al + aoff, LAl + ldsb);
      gload16(Bh + boff, LBh + ldsb);
      gload16(Bl + boff, LBl + ldsb);
    }
    __syncthreads();
    bf16x8 ah[4], al[4], bh[4], bl[4];
    #pragma unroll
    for (int i = 0; i < 4; ++i) {
      int arow = wr * 64 + i * 16 + (lane & 15);
      int abyte = arow * 64 + (((lane >> 4) ^ (arow & 3)) * 16);
      ah[i] = *(const bf16x8*)(LAh + abyte);
      al[i] = *(const bf16x8*)(LAl + abyte);
      int brow = wc * 64 + i * 16 + (lane & 15);
      int bbyte = brow * 64 + (((lane >> 4) ^ (brow & 3)) * 16);
      bh[i] = *(const bf16x8*)(LBh + bbyte);
      bl[i] = *(const bf16x8*)(LBl + bbyte);
    }
    #pragma unroll
    for (int i = 0; i < 4; ++i)
      #pragma unroll
      for (int jn = 0; jn < 4; ++jn) {
        acc[i][jn] = __builtin_amdgcn_mfma_f32_16x16x32_bf16(ah[i], bh[jn], acc[i][jn], 0, 0, 0);
        acc[i][jn] = __builtin_amdgcn_mfma_f32_16x16x32_bf16(ah[i], bl[jn], acc[i][jn], 0, 0, 0);
        acc[i][jn] = __builtin_amdgcn_mfma_f32_16x16x32_bf16(al[i], bh[jn], acc[i][jn], 0, 0, 0);
      }
    __syncthreads();
  }
  #pragma unroll
  for (int i = 0; i < 4; ++i) {
    int grow = m0 + wr * 64 + i * 16 + ((lane >> 4) << 2);
    #pragma unroll
    for (int jn = 0; jn < 4; ++jn) {
      int gcol = n0 + wc * 64 + jn * 16 + (lane & 15);
      #pragma unroll
      for (int r = 0; r < 4; ++r)
        C[(size_t)(grow + r) * KDIM + gcol] = acc[i][jn][r];
    }
  }
}

// ---------------------------------------------------------------------------
// Mobius epilogue for the big GEMM (in-place on Mx -> Ux). One block per row.
// ---------------------------------------------------------------------------
__global__ __launch_bounds__(256) void ux_epilogue(const float* __restrict__ inp,
                                                   float* __restrict__ Mx) {
  const int r = blockIdx.x;
  const int t = r >> 6, b = r & 63;
  const float* xrow = inp + ((size_t)(b * T_DIM + t)) * KDIM;
  float* mrow = Mx + (size_t)r * KDIM;
  const int tid = threadIdx.x;
  __shared__ float lds[8];
  float xs2 = 0.f, ms2 = 0.f;
  float m[8];
  #pragma unroll
  for (int j = 0; j < 8; ++j) {
    const int col = tid + j * 256;
    float xv = xrow[col] + EPSF;
    xs2 += xv * xv;
    float mv = mrow[col];
    m[j] = mv;
    ms2 += mv * mv;
  }
  block_reduce2(xs2, ms2, lds);
  float xn = sqrtf(xs2);
  float mnr = sqrtf(ms2);
  float mxn = mnr + EPSF;
  float s = tanhf((mxn / xn) * atanh_ref(xn)) / mxn;
  float na = s * mnr;
  float pf = fminf(1.0f, MAXN / fmaxf(na, EPSF));
  float sc = s * pf;
  #pragma unroll
  for (int j = 0; j < 8; ++j)
    mrow[tid + j * 256] = m[j] * sc;
}

// ---------------------------------------------------------------------------
// Scan init (runs AFTER gemm/epilogue — hx aliases the then-dead Ah/Al).
// hx slot 0 = initial h (0+EPS) bf16 hi/lo; pd all slots zeroed with slot0
// hn2 = 2048*EPS^2; bvbv scalar; flags zeroed. All normal stores —
// dispatch-boundary writeback makes them coherent for scan_coop.
// ---------------------------------------------------------------------------
__global__ __launch_bounds__(256) void scan_init(unsigned short* __restrict__ hx,
                                                 float* __restrict__ pd,
                                                 const float* __restrict__ bvec,
                                                 float* __restrict__ bvbvp,
                                                 unsigned* __restrict__ flags) {
  const int bx = blockIdx.x;  // 64 blocks, one per batch row
  const int tid = threadIdx.x;
  const unsigned short he = f2bf(EPSF);
  const unsigned short le = f2bf(EPSF - bf2f(he));
  unsigned short hv[8], lv[8];
  #pragma unroll
  for (int j = 0; j < 8; ++j) { hv[j] = he; lv[j] = le; }
  const int base = bx * KDIM + tid * 8;
  *(bf16x8*)(hx + base) = *(bf16x8*)hv;
  *(bf16x8*)(hx + 131072 + base) = *(bf16x8*)lv;
  if (bx == 0) {
    for (int i = tid; i < 256 * PDSLOT; i += 256) pd[i] = 0.0f;
    __syncthreads();
    if (tid < 64) pd[5 * 64 + tid] = 2048.0f * EPSF * EPSF;  // slot0 hn2
    if (tid < NBLK) flags[tid] = 0u;
  }
  if (bx == 1) {
    __shared__ float lds[8];
    float s = 0.f;
    #pragma unroll
    for (int j = 0; j < 8; ++j) {
      float v = bvec[tid + j * 256] + EPSF;
      s += v * v;
    }
    float dummy = 0.f;
    block_reduce2(s, dummy, lds);
    if (tid == 0) *bvbvp = s;
  }
}

// ---------------------------------------------------------------------------
// Persistent whole-scan kernel. 128 blocks x 256 threads.
// ROTATING per-step buffers: producers sc-store h into hx[(t+1)&255] and
// atomicAdd dots into pd[t]; consumers use NORMAL CACHED loads on these
// never-before-touched addresses (first touch per XCD misses to MALL, the
// other blocks on that XCD hit L2) — no stale-line hazard, no L2 fences,
// no per-step zeroing. Barriers unchanged (r7-proven drain->flag->poll).
// ---------------------------------------------------------------------------
__global__ __launch_bounds__(256) void scan_coop(const unsigned short* __restrict__ Wth,
                                                 const unsigned short* __restrict__ Wtl,
                                                 unsigned short* __restrict__ hx,
                                                 const float* __restrict__ Ux,
                                                 const float* __restrict__ bvec,
                                                 float* __restrict__ pd,
                                                 const float* __restrict__ bvbvp,
                                                 unsigned* __restrict__ flags,
                                                 float* __restrict__ out) {
  const int tid = threadIdx.x;
  const int bx = blockIdx.x;
  const int lane = tid & 63;
  const int w = tid >> 6;
  // bits[2:0]=xcd, bit3=rg, bits[6:4]=s  -> cs = xcd*8 + s (XCD-grouped)
  const int rg = (bx >> 3) & 1;
  const int cs = (bx & 7) * 8 + (bx >> 4);      // 0..63
  const int ci = cs;                            // barrier slot within rg-half
  const int gc0 = cs * 32;
  const int r = tid >> 3;                       // row within 32
  const int b = rg * 32 + r;                    // batch row
  const int gc = gc0 + (tid & 7) * 4;           // 4 cols per thread

  __shared__ float wtmp[4][32][32];
  __shared__ float MhL[32][32];
  __shared__ float red[32][6];
  __shared__ float cf[32][3];

  const float bvbv = *bvbvp;
  float bv[4];
  {
    float4 b4 = *(const float4*)(bvec + gc);
    bv[0] = b4.x + EPSF; bv[1] = b4.y + EPSF;
    bv[2] = b4.z + EPSF; bv[3] = b4.w + EPSF;
  }

  const int arow0 = (rg * 32 + (lane & 15)) * KDIM;
  const int arow1 = (rg * 32 + 16 + (lane & 15)) * KDIM;
  const int brow0 = (gc0 + (lane & 15)) * KDIM;
  const int brow1 = (gc0 + 16 + (lane & 15)) * KDIM;
  const int ksub = w * 512 + (lane >> 4) * 8;

  for (int t = 0; t < T_DIM; ++t) {
    // ---- phase A: Mh tile (32x32) via bf16x3 MFMA; h from hx[t] via
    //      normal cached loads (compiler-pipelined) ----
    const unsigned short* hxs = hx + (size_t)(t & 255) * HSLOT;
    f32x4 acc[2][2] = {};
    #pragma unroll
    for (int g = 0; g < 4; ++g) {
      #pragma unroll
      for (int q = 0; q < 4; ++q) {
        const int kq = ksub + (g * 4 + q) * 32;
        bf16x8 a0h = *(const bf16x8*)(hxs + arow0 + kq);
        bf16x8 a0l = *(const bf16x8*)(hxs + 131072 + arow0 + kq);
        bf16x8 a1h = *(const bf16x8*)(hxs + arow1 + kq);
        bf16x8 a1l = *(const bf16x8*)(hxs + 131072 + arow1 + kq);
        bf16x8 b0h = *(const bf16x8*)(Wth + brow0 + kq);
        bf16x8 b0l = *(const bf16x8*)(Wtl + brow0 + kq);
        bf16x8 b1h = *(const bf16x8*)(Wth + brow1 + kq);
        bf16x8 b1l = *(const bf16x8*)(Wtl + brow1 + kq);
        acc[0][0] = __builtin_amdgcn_mfma_f32_16x16x32_bf16(a0h, b0h, acc[0][0], 0, 0, 0);
        acc[0][0] = __builtin_amdgcn_mfma_f32_16x16x32_bf16(a0h, b0l, acc[0][0], 0, 0, 0);
        acc[0][0] = __builtin_amdgcn_mfma_f32_16x16x32_bf16(a0l, b0h, acc[0][0], 0, 0, 0);
        acc[0][1] = __builtin_amdgcn_mfma_f32_16x16x32_bf16(a0h, b1h, acc[0][1], 0, 0, 0);
        acc[0][1] = __builtin_amdgcn_mfma_f32_16x16x32_bf16(a0h, b1l, acc[0][1], 0, 0, 0);
        acc[0][1] = __builtin_amdgcn_mfma_f32_16x16x32_bf16(a0l, b1h, acc[0][1], 0, 0, 0);
        acc[1][0] = __builtin_amdgcn_mfma_f32_16x16x32_bf16(a1h, b0h, acc[1][0], 0, 0, 0);
        acc[1][0] = __builtin_amdgcn_mfma_f32_16x16x32_bf16(a1h, b0l, acc[1][0], 0, 0, 0);
        acc[1][0] = __builtin_amdgcn_mfma_f32_16x16x32_bf16(a1l, b0h, acc[1][0], 0, 0, 0);
        acc[1][1] = __builtin_amdgcn_mfma_f32_16x16x32_bf16(a1h, b1h, acc[1][1], 0, 0, 0);
        acc[1][1] = __builtin_amdgcn_mfma_f32_16x16x32_bf16(a1h, b1l, acc[1][1], 0, 0, 0);
        acc[1][1] = __builtin_amdgcn_mfma_f32_16x16x32_bf16(a1l, b1h, acc[1][1], 0, 0, 0);
      }
    }
    #pragma unroll
    for (int q = 0; q < 4; ++q) {
      const int rr = (lane >> 4) * 4 + q;
      const int cc = lane & 15;
      wtmp[w][rr][cc]           = acc[0][0][q];
      wtmp[w][rr][16 + cc]      = acc[0][1][q];
      wtmp[w][16 + rr][cc]      = acc[1][0][q];
      wtmp[w][16 + rr][16 + cc] = acc[1][1][q];
    }
    __syncthreads();
    #pragma unroll
    for (int k = 0; k < 4; ++k) {
      int e = tid + k * 256;
      int rr = e >> 5, cc = e & 31;
      MhL[rr][cc] = wtmp[0][rr][cc] + wtmp[1][rr][cc] + wtmp[2][rr][cc] + wtmp[3][rr][cc];
    }
    __syncthreads();
    float mh[4], ux[4];
    #pragma unroll
    for (int j = 0; j < 4; ++j) mh[j] = MhL[r][(tid & 7) * 4 + j];
    {
      f32x4 u4 = __builtin_nontemporal_load(
          reinterpret_cast<const f32x4*>(Ux + ((size_t)t * 64 + b) * KDIM + gc));
      ux[0] = u4[0] + EPSF; ux[1] = u4[1] + EPSF;
      ux[2] = u4[2] + EPSF; ux[3] = u4[3] + EPSF;
    }
    float dt0 = 0.f, dt1 = 0.f, dt2 = 0.f, dt3 = 0.f, dt4 = 0.f;
    #pragma unroll
    for (int j = 0; j < 4; ++j) {
      dt0 += mh[j] * mh[j];
      dt1 += mh[j] * ux[j];
      dt2 += ux[j] * ux[j];
      dt3 += mh[j] * bv[j];
      dt4 += ux[j] * bv[j];
    }
    #pragma unroll
    for (int off = 4; off > 0; off >>= 1) {
      dt0 += __shfl_down(dt0, off, 8);
      dt1 += __shfl_down(dt1, off, 8);
      dt2 += __shfl_down(dt2, off, 8);
      dt3 += __shfl_down(dt3, off, 8);
      dt4 += __shfl_down(dt4, off, 8);
    }
    float* pdt = pd + (size_t)t * PDSLOT;
    if ((tid & 7) == 0) {
      float dts[5] = {dt0, dt1, dt2, dt3, dt4};
      #pragma unroll
      for (int v = 0; v < 5; ++v)
        __hip_atomic_fetch_add(pdt + v * 64 + b, dts[v],
                               __ATOMIC_RELAXED, __HIP_MEMORY_SCOPE_AGENT);
    }
    gbar3(flags, rg, ci, (unsigned)(2 * t + 1));

    // ---- phase B: read dots (normal cached; final at MALL pre-barrier) ----
    if (tid < 192) {
      int v = tid >> 5, rr = tid & 31;
      red[rr][v] = pdt[v * 64 + rg * 32 + rr];
    }
    __syncthreads();
    if (tid < 32) {
      const float mn2 = red[tid][0], Mhux = red[tid][1], uxux = red[tid][2];
      const float Mhbv = red[tid][3], uxbv = red[tid][4], hn2 = red[tid][5];
      const float hn = sqrtf(hn2);
      const float mnr = sqrtf(mn2);
      const float mxn = mnr + EPSF;
      const float s = tanhf((mxn / hn) * atanh_ref(hn)) / mxn;
      const float n_a = s * mnr;
      const float pfa = fminf(1.0f, MAXN / fmaxf(n_a, EPSF));
      const float sa = s * pfa;
      const float duv = 2.0f * sa * Mhux;
      const float nv = uxux;
      const float na = sa * sa * mn2;
      const float denom = 1.0f + duv + na * nv;
      const float c1 = (1.0f + duv + nv) / denom;
      const float c2 = (1.0f - na) / denom;
      const float r1n2 = c1 * c1 * na + 2.0f * c1 * c2 * sa * Mhux + c2 * c2 * uxux;
      const float pf1 = fminf(1.0f, MAXN / fmaxf(sqrtf(r1n2), EPSF));
      const float Sr1bv = c1 * sa * Mhbv + c2 * uxbv;
      const float duv2 = 2.0f * pf1 * Sr1bv;
      const float na2 = pf1 * pf1 * r1n2;
      const float denom2 = 1.0f + duv2 + na2 * bvbv;
      const float d1 = (1.0f + duv2 + bvbv) / denom2;
      const float d2 = (1.0f - na2) / denom2;
      const float r2n2 = d1 * d1 * na2 + 2.0f * d1 * d2 * pf1 * Sr1bv + d2 * d2 * bvbv;
      const float pf2 = fminf(1.0f, MAXN / fmaxf(sqrtf(r2n2), EPSF));
      cf[tid][0] = pf2 * d1 * pf1 * c1 * sa;  // K_mh
      cf[tid][1] = pf2 * d1 * pf1 * c2;       // K_ux
      cf[tid][2] = pf2 * d2;                  // K_bv
    }
    __syncthreads();
    const float Km = cf[r][0], Ku = cf[r][1], Kb = cf[r][2];
    float hv[4];
    #pragma unroll
    for (int j = 0; j < 4; ++j) hv[j] = Km * mh[j] + Ku * ux[j] + Kb * bv[j];
    {
      f32x4 o4;
      o4[0] = hv[0]; o4[1] = hv[1]; o4[2] = hv[2]; o4[3] = hv[3];
      __builtin_nontemporal_store(
          o4, reinterpret_cast<f32x4*>(out + ((size_t)b * T_DIM + t) * KDIM + gc));
    }
    unsigned short eb[4], lb[4];
    float hn2p = 0.f;
    #pragma unroll
    for (int j = 0; j < 4; ++j) {
      float hp = hv[j] + EPSF;
      eb[j] = f2bf(hp);
      lb[j] = f2bf(hp - bf2f(eb[j]));
      hn2p += hp * hp;
    }
    uint32x2 hhu, hlu;
    hhu[0] = (unsigned)eb[0] | ((unsigned)eb[1] << 16);
    hhu[1] = (unsigned)eb[2] | ((unsigned)eb[3] << 16);
    hlu[0] = (unsigned)lb[0] | ((unsigned)lb[1] << 16);
    hlu[1] = (unsigned)lb[2] | ((unsigned)lb[3] << 16);
    unsigned short* hxn = hx + (size_t)((t + 1) & 255) * HSLOT;
    stg_sc8(hxn + b * KDIM + gc, hhu);            // write-through to MALL
    stg_sc8(hxn + 131072 + b * KDIM + gc, hlu);
    #pragma unroll
    for (int off = 4; off > 0; off >>= 1) hn2p += __shfl_down(hn2p, off, 8);
    if ((tid & 7) == 0)
      __hip_atomic_fetch_add(pd + (size_t)((t + 1) & 255) * PDSLOT + 5 * 64 + b, hn2p,
                             __ATOMIC_RELAXED, __HIP_MEMORY_SCOPE_AGENT);
    gbar3(flags, rg, ci, (unsigned)(2 * t + 2));
  }
}

// ---------------------------------------------------------------------------
// Fallback kernels (small-workspace paths).
// ---------------------------------------------------------------------------
__global__ __launch_bounds__(256) void gemm64_splitk(const float* __restrict__ A,
                                                     size_t arstride,
                                                     const float* __restrict__ Bm,
                                                     float* __restrict__ part) {
  const int n0 = blockIdx.x * 64;
  const int kz = blockIdx.y;
  const int kbeg = kz * 256;
  __shared__ float As[16][68];
  __shared__ float Bs[16][64];
  const int tid = threadIdx.x;
  const int tx = tid & 15, ty = tid >> 4;
  const int ai = tid >> 2, ak = (tid & 3) * 4;
  const int bk = tid >> 4, bn = (tid & 15) * 4;
  const float* Arow = A + (size_t)ai * arstride;
  float acc[4][4] = {};
  for (int kt = 0; kt < 16; ++kt) {
    const int k0 = kbeg + kt * 16;
    float4 av = *(const float4*)(Arow + k0 + ak);
    As[ak + 0][ai] = av.x + EPSF;
    As[ak + 1][ai] = av.y + EPSF;
    As[ak + 2][ai] = av.z + EPSF;
    As[ak + 3][ai] = av.w + EPSF;
    float4 bv = *(const float4*)(Bm + (size_t)(k0 + bk) * KDIM + n0 + bn);
    *(float4*)&Bs[bk][bn] = bv;
    __syncthreads();
    #pragma unroll
    for (int k = 0; k < 16; ++k) {
      float4 a4 = *(const float4*)&As[k][ty * 4];
      float4 b4 = *(const float4*)&Bs[k][tx * 4];
      float a[4] = {a4.x, a4.y, a4.z, a4.w};
      float bb[4] = {b4.x, b4.y, b4.z, b4.w};
      #pragma unroll
      for (int i = 0; i < 4; ++i)
        #pragma unroll
        for (int j = 0; j < 4; ++j)
          acc[i][j] = fmaf(a[i], bb[j], acc[i][j]);
    }
    __syncthreads();
  }
  #pragma unroll
  for (int i = 0; i < 4; ++i) {
    float4 o = make_float4(acc[i][0], acc[i][1], acc[i][2], acc[i][3]);
    *(float4*)(part + ((size_t)kz * 64 + ty * 4 + i) * KDIM + n0 + tx * 4) = o;
  }
}

__global__ __launch_bounds__(256) void mob_from_parts(const float* __restrict__ part,
                                                      const float* __restrict__ xbase,
                                                      size_t xstride,
                                                      float* __restrict__ outrows) {
  const int b = blockIdx.x;
  const int tid = threadIdx.x;
  __shared__ float lds[8];
  const float* xrow = xbase + (size_t)b * xstride;
  float xs2 = 0.f, ms2 = 0.f;
  float m[8];
  #pragma unroll
  for (int j = 0; j < 8; ++j) {
    const int col = tid + j * 256;
    float xv = xrow[col] + EPSF;
    xs2 += xv * xv;
    float mv = 0.f;
    for (int kz = 0; kz < 8; ++kz)
      mv += part[((size_t)kz * 64 + b) * KDIM + col];
    m[j] = mv;
    ms2 += mv * mv;
  }
  block_reduce2(xs2, ms2, lds);
  float xn = sqrtf(xs2);
  float mnr = sqrtf(ms2);
  float mxn = mnr + EPSF;
  float s = tanhf((mxn / xn) * atanh_ref(xn)) / mxn;
  float na = s * mnr;
  float pf = fminf(1.0f, MAXN / fmaxf(na, EPSF));
  float sc = s * pf;
  #pragma unroll
  for (int j = 0; j < 8; ++j)
    outrows[(size_t)b * KDIM + tid + j * 256] = m[j] * sc;
}

__global__ __launch_bounds__(256) void step_mobius(const float* __restrict__ part,
                                                   float* __restrict__ h,
                                                   const float* __restrict__ uxrows,
                                                   const float* __restrict__ bvec,
                                                   float* __restrict__ out,
                                                   int t) {
  const int b = blockIdx.x;
  const int tid = threadIdx.x;
  __shared__ float lds[8];
  float mh[8], uxv[8], bv[8];
  float hn2 = 0.f, mn2 = 0.f;
  #pragma unroll
  for (int j = 0; j < 8; ++j) {
    const int col = tid + j * 256;
    float x = h[(size_t)b * KDIM + col] + EPSF;
    hn2 += x * x;
    float m = 0.f;
    for (int kz = 0; kz < 8; ++kz)
      m += part[((size_t)kz * 64 + b) * KDIM + col];
    mh[j] = m;
    mn2 += m * m;
    uxv[j] = uxrows[(size_t)b * KDIM + col] + EPSF;
    bv[j] = bvec[col] + EPSF;
  }
  block_reduce2(hn2, mn2, lds);
  float hn = sqrtf(hn2);
  float mnr = sqrtf(mn2);
  float mxn = mnr + EPSF;
  float s = tanhf((mxn / hn) * atanh_ref(hn)) / mxn;
  float n_a = s * mnr;
  float pfa = fminf(1.0f, MAXN / fmaxf(n_a, EPSF));
  float sa = s * pfa;
  float a[8];
  float duv = 0.f, nv = 0.f;
  #pragma unroll
  for (int j = 0; j < 8; ++j) {
    a[j] = sa * mh[j];
    duv += a[j] * uxv[j];
    nv += uxv[j] * uxv[j];
  }
  block_reduce2(duv, nv, lds);
  duv *= 2.0f;
  float na = sa * sa * mn2;
  float denom = 1.0f + duv + na * nv;
  float c1 = (1.0f + duv + nv) / denom;
  float c2 = (1.0f - na) / denom;
  float r1[8];
  float r1n2 = 0.f, dummy = 0.f;
  #pragma unroll
  for (int j = 0; j < 8; ++j) {
    r1[j] = c1 * a[j] + c2 * uxv[j];
    r1n2 += r1[j] * r1[j];
  }
  block_reduce2(r1n2, dummy, lds);
  float n1 = sqrtf(r1n2);
  float pf1 = fminf(1.0f, MAXN / fmaxf(n1, EPSF));
  float duv2 = 0.f, nv2 = 0.f;
  #pragma unroll
  for (int j = 0; j < 8; ++j) {
    r1[j] *= pf1;
    duv2 += r1[j] * bv[j];
    nv2 += bv[j] * bv[j];
  }
  block_reduce2(duv2, nv2, lds);
  duv2 *= 2.0f;
  float na2 = pf1 * pf1 * r1n2;
  float denom2 = 1.0f + duv2 + na2 * nv2;
  float d1 = (1.0f + duv2 + nv2) / denom2;
  float d2 = (1.0f - na2) / denom2;
  float r2[8];
  float r2n2 = 0.f;
  dummy = 0.f;
  #pragma unroll
  for (int j = 0; j < 8; ++j) {
    r2[j] = d1 * r1[j] + d2 * bv[j];
    r2n2 += r2[j] * r2[j];
  }
  block_reduce2(r2n2, dummy, lds);
  float n2 = sqrtf(r2n2);
  float pf2 = fminf(1.0f, MAXN / fmaxf(n2, EPSF));
  #pragma unroll
  for (int j = 0; j < 8; ++j) {
    const int col = tid + j * 256;
    float vout = r2[j] * pf2;
    h[(size_t)b * KDIM + col] = vout;
    out[((size_t)b * T_DIM + t) * KDIM + col] = vout;
  }
}

extern "C" void kernel_launch(void* const* d_in, const int* in_sizes, int n_in,
                              void* d_out, int out_size, void* d_ws, size_t ws_size,
                              hipStream_t stream) {
  const float* inp  = (const float*)d_in[0];
  const float* wm   = (const float*)d_in[1];
  const float* um   = (const float*)d_in[2];
  const float* bvec = (const float*)d_in[3];
  float* out = (float*)d_out;
  char* ws = (char*)d_ws;

  const size_t UXB  = (size_t)TBROWS * KDIM * 4;   // 134.2 MB
  const size_t AHL  = (size_t)TBROWS * KDIM * 2;   // 67.1 MB (x2 = hx arena)
  const size_t BTB  = (size_t)KDIM * KDIM * 2;     // 8.4 MB
  const size_t PDB  = (size_t)256 * PDSLOT * 4;    // 393 KB
  const size_t META = 2048;                        // bvbv + flags
  const size_t HFP  = (size_t)B_DIM * KDIM * 4;    // 512 KB
  const size_t PART = (size_t)8 * B_DIM * KDIM * 4; // 4 MB

  size_t off = 0;
  float* Ux = (float*)(ws + off); off += UXB;
  unsigned short* Ah = (unsigned short*)(ws + off);       // hx aliases Ah+Al
  unsigned short* hx = Ah; off += AHL;
  unsigned short* Al = (unsigned short*)(ws + off); off += AHL;
  unsigned short* Bh = (unsigned short*)(ws + off); off += BTB;
  unsigned short* Bl = (unsigned short*)(ws + off); off += BTB;
  unsigned short* Wth = (unsigned short*)(ws + off); off += BTB;
  unsigned short* Wtl = (unsigned short*)(ws + off); off += BTB;
  float* pd = (float*)(ws + off); off += PDB;
  float* bvbvp = (float*)(ws + off);
  unsigned* flagsp = (unsigned*)(ws + off + 128); off += META;
  float* hfp = (float*)(ws + off); off += HFP;
  float* part = (float*)(ws + off); off += PART;
  const size_t NEED_COOP = off;
  const size_t NEED_MFMA = UXB + 2 * AHL + 2 * BTB + HFP + PART;
  const size_t NEED_FP32 = UXB + HFP + PART;

  if (ws_size >= NEED_COOP) {
    convert_a<<<TBROWS, 256, 0, stream>>>(inp, Ah, Al);
    convert_bt<<<dim3(32, 32), 256, 0, stream>>>(um, Bh, Bl);
    convert_bt<<<dim3(32, 32), 256, 0, stream>>>(wm, Wth, Wtl);
    gemm_mfma3<<<dim3(128, 16), 256, 0, stream>>>(Ah, Al, Bh, Bl, Ux);
    ux_epilogue<<<TBROWS, 256, 0, stream>>>(inp, Ux);
    // scan_init AFTER the GEMM: hx slot 0 overwrites (now-dead) Ah rows.
    scan_init<<<B_DIM, 256, 0, stream>>>(hx, pd, bvec, bvbvp, flagsp);
    scan_coop<<<NBLK, 256, 0, stream>>>(Wth, Wtl, hx, Ux, bvec, pd, bvbvp,
                                        flagsp, out);
  } else if (ws_size >= NEED_MFMA) {
    float* Ux2 = (float*)ws;
    unsigned short* Ah2 = (unsigned short*)(ws + UXB);
    unsigned short* Al2 = (unsigned short*)(ws + UXB + AHL);
    unsigned short* Bh2 = (unsigned short*)(ws + UXB + 2 * AHL);
    unsigned short* Bl2 = (unsigned short*)(ws + UXB + 2 * AHL + BTB);
    float* h2 = (float*)(ws + UXB + 2 * AHL + 2 * BTB);
    float* part2 = (float*)(ws + UXB + 2 * AHL + 2 * BTB + HFP);
    hipMemsetAsync(h2, 0, HFP, stream);
    convert_a<<<TBROWS, 256, 0, stream>>>(inp, Ah2, Al2);
    convert_bt<<<dim3(32, 32), 256, 0, stream>>>(um, Bh2, Bl2);
    gemm_mfma3<<<dim3(128, 16), 256, 0, stream>>>(Ah2, Al2, Bh2, Bl2, Ux2);
    ux_epilogue<<<TBROWS, 256, 0, stream>>>(inp, Ux2);
    for (int t = 0; t < T_DIM; ++t) {
      gemm64_splitk<<<dim3(32, 8), 256, 0, stream>>>(h2, (size_t)KDIM, wm, part2);
      step_mobius<<<B_DIM, 256, 0, stream>>>(part2, h2, Ux2 + (size_t)t * B_DIM * KDIM,
                                             bvec, out, t);
    }
  } else {
    float* h2 = (float*)ws;
    float* part2 = (float*)(ws + HFP);
    float* partU = (float*)(ws + HFP + PART);
    float* uxstep = (float*)(ws + HFP + 2 * PART);
    hipMemsetAsync(h2, 0, HFP, stream);
    for (int t = 0; t < T_DIM; ++t) {
      const float* xt = inp + (size_t)t * KDIM;
      gemm64_splitk<<<dim3(32, 8), 256, 0, stream>>>(xt, (size_t)T_DIM * KDIM, um, partU);
      mob_from_parts<<<B_DIM, 256, 0, stream>>>(partU, xt, (size_t)T_DIM * KDIM, uxstep);
      gemm64_splitk<<<dim3(32, 8), 256, 0, stream>>>(h2, (size_t)KDIM, wm, part2);
      step_mobius<<<B_DIM, 256, 0, stream>>>(part2, h2, uxstep, bvec, out, t);
    }
  }
}